// Round 13
// baseline (1181.506 us; speedup 1.0000x reference)
//
#include <hip/hip_runtime.h>
#include <hip/hip_bf16.h>
#include <math.h>

// GPT-1 forward: B=2 S=512 D=768 H=12 DFF=3072 L=12 V=32000
constexpr int BATCH = 2;
constexpr int SEQ   = 512;
constexpr int DM    = 768;
constexpr int NH    = 12;
constexpr int FF    = 3072;
constexpr int NL    = 12;
constexpr int NV    = 32000;
constexpr int HD    = 64;
constexpr int MT    = BATCH * SEQ; // 1024 token rows
constexpr int QKV   = 3 * DM;      // 2304

typedef __attribute__((ext_vector_type(8))) short bf16x8;
typedef __attribute__((ext_vector_type(4))) float f32x4;

__device__ __forceinline__ float b2f(ushort u) {
    return __uint_as_float(((unsigned)u) << 16);
}
__device__ __forceinline__ ushort f2b(float f) {
    __hip_bfloat16 h = __float2bfloat16(f);
    return *reinterpret_cast<ushort*>(&h);
}

template<int N>
__device__ __forceinline__ void waitcnt_vm() {
    if constexpr (N == 0) asm volatile("s_waitcnt vmcnt(0)" ::: "memory");
    else if constexpr (N == 2) asm volatile("s_waitcnt vmcnt(2)" ::: "memory");
    else if constexpr (N == 3) asm volatile("s_waitcnt vmcnt(3)" ::: "memory");
    else if constexpr (N == 4) asm volatile("s_waitcnt vmcnt(4)" ::: "memory");
    else if constexpr (N == 6) asm volatile("s_waitcnt vmcnt(6)" ::: "memory");
    else if constexpr (N == 8) asm volatile("s_waitcnt vmcnt(8)" ::: "memory");
    else if constexpr (N == 12) asm volatile("s_waitcnt vmcnt(12)" ::: "memory");
    else if constexpr (N == 16) asm volatile("s_waitcnt vmcnt(16)" ::: "memory");
}

// ---------------------------------------------------------------- embedding
__global__ void embed_kernel(const int* __restrict__ tokens,
                             const float* __restrict__ tok_emb,
                             const float* __restrict__ pos_emb,
                             float* __restrict__ x) {
    int m = blockIdx.x;
    int s = m % SEQ;
    int t = tokens[m];
    const float* te = tok_emb + (size_t)t * DM;
    const float* pe = pos_emb + (size_t)s * DM;
    float* row = x + (size_t)m * DM;
    for (int d = threadIdx.x; d < DM; d += blockDim.x)
        row[d] = te[d] + pe[d];
}

// ------------------------------------------------- weight convert+transpose
// in: f32 [l][K][N]; out: bf16 [l][N][K]. Tile 64 n x 128 k.
__global__ __launch_bounds__(256) void wconv_kernel(
        const float* __restrict__ W, ushort* __restrict__ out,
        int K, int N, size_t inLS, size_t outLS, int nOff) {
    int l  = blockIdx.z;
    int n0 = blockIdx.x * 64;
    int k0 = blockIdx.y * 128;
    int tid = threadIdx.x;
    __shared__ float t[2][64][65];   // [k-half][k%64][n]
    const float* src = W + (size_t)l * inLS + (size_t)k0 * N + n0;
    int r  = tid >> 4;           // 0..15
    int c4 = (tid & 15) * 4;     // 0..60
#pragma unroll
    for (int i = 0; i < 8; i++) {
        int krow = i * 16 + r;           // 0..127
        float4 v = *(const float4*)(src + (size_t)krow * N + c4);
        float* dstl = &t[krow >> 6][krow & 63][c4];
        dstl[0] = v.x; dstl[1] = v.y; dstl[2] = v.z; dstl[3] = v.w;
    }
    __syncthreads();
    ushort* dst = out + (size_t)l * outLS;
    int kk = (tid & 15) * 8;     // 0..120 (lane's 8-elem k chunk)
    int h  = kk >> 6;            // half
    int kb = kk & 63;
#pragma unroll
    for (int j = 0; j < 4; j++) {
        int n = j * 16 + (tid >> 4);     // 0..63
        ushort o[8];
#pragma unroll
        for (int m = 0; m < 8; m++) o[m] = f2b(t[h][kb + m][n]);
        *(ushort4*)(dst + (size_t)(nOff + n0 + n) * K + k0 + kk)     = *(ushort4*)&o[0];
        *(ushort4*)(dst + (size_t)(nOff + n0 + n) * K + k0 + kk + 4) = *(ushort4*)&o[4];
    }
}

// ---------------------------------------------------------------- bias pack
__global__ void biaspack_kernel(const float* __restrict__ bq,
                                const float* __restrict__ bk,
                                const float* __restrict__ bv,
                                float* __restrict__ bqkv) {
    int idx = blockIdx.x * 256 + threadIdx.x;
    if (idx >= NL * QKV) return;
    int l = idx / QKV, c = idx % QKV;
    float v;
    if (c < DM)            v = bq[l * DM + c];
    else if (c < 2 * DM)   v = bk[l * DM + c - DM];
    else                   v = bv[l * DM + c - 2 * DM];
    bqkv[idx] = v;
}

// ---------------------------------------------------------------- f32->bf16
__global__ void cvt_kernel(const float* __restrict__ in, ushort* __restrict__ out, int n) {
    int i = blockIdx.x * 256 + threadIdx.x;
    if (i < n) out[i] = f2b(in[i]);
}

// ---------------------------------------------------------------- layernorm
__global__ __launch_bounds__(256) void ln_kernel(const float* __restrict__ x,
                                                 const float* __restrict__ sc,
                                                 const float* __restrict__ bi,
                                                 ushort* __restrict__ y) {
    int m = blockIdx.x;
    int t = threadIdx.x;
    const float* row = x + (size_t)m * DM;
    float vals[3];
    float s0 = 0.f, s1 = 0.f;
#pragma unroll
    for (int i = 0; i < 3; i++) {
        float v = row[t + 256 * i];
        vals[i] = v;
        s0 += v;
        s1 += v * v;
    }
#pragma unroll
    for (int off = 32; off >= 1; off >>= 1) {
        s0 += __shfl_down(s0, off, 64);
        s1 += __shfl_down(s1, off, 64);
    }
    __shared__ float r0[4], r1[4];
    __shared__ float mu_s, rs_s;
    int wid = t >> 6, lane = t & 63;
    if (lane == 0) { r0[wid] = s0; r1[wid] = s1; }
    __syncthreads();
    if (t == 0) {
        float a = r0[0] + r0[1] + r0[2] + r0[3];
        float q = r1[0] + r1[1] + r1[2] + r1[3];
        float mu  = a / DM;
        float var = q / DM - mu * mu;
        mu_s = mu;
        rs_s = rsqrtf(var + 1e-5f);
    }
    __syncthreads();
    float mu = mu_s, rs = rs_s;
    ushort* orow = y + (size_t)m * DM;
#pragma unroll
    for (int i = 0; i < 3; i++) {
        int d = t + 256 * i;
        orow[d] = f2b((vals[i] - mu) * rs * sc[d] + bi[d]);
    }
}

// ---------------------------------------------------------------- MFMA GEMM
__device__ __forceinline__ void gload_lds16(const void* g, void* l) {
    __builtin_amdgcn_global_load_lds(
        (const __attribute__((address_space(1))) void*)g,
        (__attribute__((address_space(3))) void*)l, 16, 0, 0);
}

template<int BM, int BN, int WM, int WN, int KSTEP, int NBUF, int SPLITK, int ACT,
         bool RES, bool WF32, bool WBF16, bool VT, bool ATOMIC>
__device__ __forceinline__ void gemm_body(
        const ushort* __restrict__ A, const ushort* __restrict__ BT,
        const float* __restrict__ bias, const float* __restrict__ res,
        float* __restrict__ Cf, ushort* __restrict__ Cb, ushort* __restrict__ Vt,
        int M, int N, int K) {
    constexpr int THREADS = WM * WN * 64;
    constexpr int ROWS    = BM + BN;
    constexpr int SEGS    = KSTEP / 8;           // 16B segments per row
    constexpr int SEGSH   = (KSTEP == 32) ? 2 : 3;
    constexpr int RND     = ROWS * KSTEP / (THREADS * 8);
    constexpr int MR      = BM / WM / 16;
    constexpr int NR      = BN / WN / 16;
    constexpr int KCH     = KSTEP / 32;          // mfma k-subtiles per step
    constexpr int STRIDE  = ROWS * KSTEP;        // ushorts per buffer
    __shared__ ushort S_lds[NBUF * STRIDE];
    int tid = threadIdx.x;
    int il = tid & 63, wv = tid >> 6;

    // bijective XCD-chunked swizzle
    int p   = blockIdx.x + gridDim.x * blockIdx.y;
    int nwg = gridDim.x * gridDim.y;
    int q8  = nwg >> 3, r8 = nwg & 7;
    int xcd = p & 7, k8 = p >> 3;
    int orig = (xcd < r8 ? xcd * (q8 + 1) : r8 * (q8 + 1) + (xcd - r8) * q8) + k8;
    int bx = orig / gridDim.y;       // n-tile  (y-major)
    int by = orig % gridDim.y;       // m-tile
    int bm = by * BM, bn = bx * BN;

    int kLen  = K / SPLITK;
    int kBase = blockIdx.z * kLen;

    auto swz = [](int row) -> int {
        return (KSTEP == 32) ? ((row >> 1) & 3) : (row & 7);
    };

    const ushort* src[RND];
    int dstOff[RND];
#pragma unroll
    for (int r = 0; r < RND; r++) {
        int f = r * THREADS + tid;
        int row = f >> SEGSH, seg = f & (SEGS - 1);
        int lseg = seg ^ swz(row);
        src[r] = (row < BM ? A + (size_t)(bm + row) * K
                           : BT + (size_t)(bn + row - BM) * K) + kBase + lseg * 8;
        dstOff[r] = (r * THREADS + wv * 64) * 8;
    }

    int wm = wv / WN, wn = wv % WN;
    int lr = il & 15;
    int lg = il >> 4;
    int swzR = swz(lr);
    f32x4 acc[MR][NR] = {};

    int nt = kLen / KSTEP;

    // prologue: stage tiles 0..NBUF-2
#pragma unroll
    for (int b = 0; b < NBUF - 1; b++)
#pragma unroll
        for (int r = 0; r < RND; r++)
            gload_lds16(src[r] + b * KSTEP, &S_lds[b * STRIDE + dstOff[r]]);
    waitcnt_vm<RND * (NBUF - 2)>();
    __builtin_amdgcn_s_barrier();

    int cur = 0;
    for (int t = 0; t < nt; ++t) {
        if (t + NBUF - 1 < nt) {
            int sb = cur + NBUF - 1; if (sb >= NBUF) sb -= NBUF;
            int kofs = (t + NBUF - 1) * KSTEP;
            ushort* Bp = &S_lds[sb * STRIDE];
#pragma unroll
            for (int r = 0; r < RND; r++) gload_lds16(src[r] + kofs, &Bp[dstOff[r]]);
        }

        const ushort* base = &S_lds[cur * STRIDE];
        bf16x8 af[KCH][MR], bfr[KCH][NR];
#pragma unroll
        for (int kk = 0; kk < KCH; kk++) {
            int phys = ((kk * 4 + lg) ^ swzR) * 8;
#pragma unroll
            for (int i = 0; i < MR; i++)
                af[kk][i] = *(const bf16x8*)&base[(wm * (BM / WM) + i * 16 + lr) * KSTEP + phys];
#pragma unroll
            for (int i = 0; i < NR; i++)
                bfr[kk][i] = *(const bf16x8*)&base[(BM + wn * (BN / WN) + i * 16 + lr) * KSTEP + phys];
        }
        __builtin_amdgcn_s_setprio(1);
#pragma unroll
        for (int kk = 0; kk < KCH; kk++)
#pragma unroll
            for (int mi = 0; mi < MR; mi++)
#pragma unroll
                for (int ni = 0; ni < NR; ni++)
                    acc[mi][ni] = __builtin_amdgcn_mfma_f32_16x16x32_bf16(
                        af[kk][mi], bfr[kk][ni], acc[mi][ni], 0, 0, 0);
        __builtin_amdgcn_s_setprio(0);

        if (t + 1 < nt) {
            int k = nt - t - 2;
            if (k > NBUF - 2) k = NBUF - 2;
            switch (k) {
                case 0:  waitcnt_vm<0>(); break;
                case 1:  waitcnt_vm<RND>(); break;
                default: waitcnt_vm<2 * RND>(); break;
            }
            __builtin_amdgcn_s_barrier();
        }
        cur = (cur + 1 == NBUF) ? 0 : cur + 1;
    }

    bool addBias = bias && (SPLITK == 1 || blockIdx.z == 0);
#pragma unroll
    for (int mi = 0; mi < MR; mi++) {
        int row0 = bm + wm * (BM / WM) + mi * 16 + (il >> 4) * 4;
#pragma unroll
        for (int ni = 0; ni < NR; ni++) {
            int col = bn + wn * (BN / WN) + ni * 16 + (il & 15);
            float bv = addBias ? bias[col] : 0.f;
#pragma unroll
            for (int j = 0; j < 4; j++) {
                int r = row0 + j;
                float v = acc[mi][ni][j] + bv;
                if (ACT == 1) v = 0.5f * v * (1.0f + erff(v * 0.70710678118654752f));
                if (RES) v += res[(size_t)r * N + col];
                if (ATOMIC) atomicAdd(&Cf[(size_t)r * N + col], v);
                else if (WF32) Cf[(size_t)r * N + col] = v;
                if (WBF16) {
                    if (VT && bn >= 2 * DM) {
                        int d  = col - 2 * DM;
                        int hh = d >> 6, dd = d & 63;
                        int bb = r >> 9, s = r & (SEQ - 1);
                        Vt[((size_t)(bb * NH + hh) * HD + dd) * SEQ + s] = f2b(v);
                    } else {
                        Cb[(size_t)r * N + col] = f2b(v);
                    }
                }
            }
        }
    }
}

// named wrappers; layer GEMMs: 64x64, KSTEP=64, NBUF=3 (proven R12).
// logits: 128x256, KSTEP=32, NBUF=3 -> 72KB LDS -> 2 blocks/CU so prologue/
// epilogue of one block overlaps compute of the other (m114).
__global__ __launch_bounds__(256) void gemm_qkv(
        const ushort* A, const ushort* BT, const float* bias,
        ushort* Cb, ushort* Vt, int M, int N, int K) {
    gemm_body<64, 64, 2, 2, 64, 3, 1, 0, false, false, true, true, false>(
        A, BT, bias, nullptr, nullptr, Cb, Vt, M, N, K);
}
__global__ __launch_bounds__(256) void gemm_wo(
        const ushort* A, const ushort* BT, const float* bias,
        float* Cf, int M, int N, int K) {
    gemm_body<64, 64, 2, 2, 64, 3, 3, 0, false, false, false, false, true>(
        A, BT, bias, nullptr, Cf, nullptr, nullptr, M, N, K);
}
__global__ __launch_bounds__(256) void gemm_w1(
        const ushort* A, const ushort* BT, const float* bias,
        ushort* Cb, int M, int N, int K) {
    gemm_body<64, 64, 2, 2, 64, 3, 1, 1, false, false, true, false, false>(
        A, BT, bias, nullptr, nullptr, Cb, nullptr, M, N, K);
}
__global__ __launch_bounds__(256) void gemm_w2(
        const ushort* A, const ushort* BT, const float* bias,
        float* Cf, int M, int N, int K) {
    gemm_body<64, 64, 2, 2, 64, 3, 3, 0, false, false, false, false, true>(
        A, BT, bias, nullptr, Cf, nullptr, nullptr, M, N, K);
}
__global__ __launch_bounds__(512, 4) void gemm_logits(
        const ushort* A, const ushort* BT, const float* bias,
        float* Cf, int M, int N, int K) {
    gemm_body<128, 256, 2, 4, 32, 3, 1, 0, false, true, false, false, false>(
        A, BT, bias, nullptr, Cf, nullptr, nullptr, M, N, K);
}

// ---------------------------------------------------------------- flash attn
// Block: 16 q-rows of one (b,h); 4 waves, 4-way key-split: wave g owns keys
// [g*128, g*128+128) (2 tiles of 64). K/V tiles are WAVE-PRIVATE in LDS ->
// zero barriers in the main loop (same-wave ds ordering via lgkmcnt only).
// Fragment math identical to proven R12 kernel. Fixed-shift softmax.
// 4-way merge through LDS at the end. 72KB LDS -> 2 independent blocks/CU.
__device__ __forceinline__ char* swzp(void* base, int row, int colByte) {
    return (char*)base + ((row * 128 + colByte) ^ ((row & 7) << 4));
}
__device__ __forceinline__ const char* swzpc(const void* base, int row, int colByte) {
    return (const char*)base + ((row * 128 + colByte) ^ ((row & 7) << 4));
}

__global__ __launch_bounds__(256) void fattn_kernel(
        const ushort* __restrict__ qkv, const ushort* __restrict__ vt,
        ushort* __restrict__ ctx) {
    int qt = blockIdx.x;   // 0..31 (16 q-rows each)
    int h  = blockIdx.y;
    int b  = blockIdx.z;
    int tid = threadIdx.x;
    int il = tid & 63, wv = tid >> 6;   // wv = key-group 0..3

    __shared__ __align__(16) char smem[72 * 1024];
    ushort* Ks = (ushort*)(smem + wv * 16384);          // [64 keys][64 d]
    ushort* Vs = (ushort*)(smem + wv * 16384 + 8192);   // [64 d][64 keys]
    ushort* Ps = (ushort*)(smem + 65536 + wv * 2048);   // [16 q][64 keys]
    float*  Om = (float*)smem;                          // [4][16][64] alias
    float*  Ss = (float*)(smem + 16384);                // [4][16]

    int bh = b * NH + h;
    const ushort* kbase = qkv + (size_t)b * SEQ * QKV + DM + h * HD;
    const ushort* vbase = vt + (size_t)bh * HD * SEQ;

    int lr = il & 15, lg = il >> 4;
    int qrow = qt * 16 + lr;
    const ushort* qptr = qkv + (size_t)(b * SEQ + qrow) * QKV + h * HD + lg * 8;
    bf16x8 qf0 = *(const bf16x8*)qptr;
    bf16x8 qf1 = *(const bf16x8*)(qptr + 32);

    f32x4 accO[4] = {};
    float sm[4] = {0.f, 0.f, 0.f, 0.f};

    int srow = il >> 3;          // 0..7
    int sseg = (il & 7) * 8;     // 0..56

    for (int kt = 0; kt < 2; kt++) {
        int k0 = wv * 128 + kt * 64;
        // stage this wave's K/V tile (wave-private; no barrier)
#pragma unroll
        for (int r = 0; r < 8; r++) {
            int row = r * 8 + srow;
            bf16x8 kv = *(const bf16x8*)(kbase + (size_t)(k0 + row) * QKV + sseg);
            bf16x8 vv = *(const bf16x8*)(vbase + (size_t)row * SEQ + k0 + sseg);
            *(bf16x8*)swzp(Ks, row, sseg * 2) = kv;
            *(bf16x8*)swzp(Vs, row, sseg * 2) = vv;
        }

        // QK^T: S[q 16][key 64]
        f32x4 accS[4] = {};
        __builtin_amdgcn_s_setprio(1);
#pragma unroll
        for (int nf = 0; nf < 4; nf++) {
            bf16x8 b0 = *(const bf16x8*)swzpc(Ks, nf * 16 + lr, lg * 16);
            bf16x8 b1 = *(const bf16x8*)swzpc(Ks, nf * 16 + lr, 64 + lg * 16);
            accS[nf] = __builtin_amdgcn_mfma_f32_16x16x32_bf16(qf0, b0, accS[nf], 0, 0, 0);
            accS[nf] = __builtin_amdgcn_mfma_f32_16x16x32_bf16(qf1, b1, accS[nf], 0, 0, 0);
        }
        __builtin_amdgcn_s_setprio(0);

        // P = exp(s*0.125 - 8); row-sum only (no max tracking)
        float pv[4][4];
#pragma unroll
        for (int nf = 0; nf < 4; nf++)
#pragma unroll
            for (int j = 0; j < 4; j++)
                pv[nf][j] = __expf(fmaf(accS[nf][j], 0.125f, -8.0f));
#pragma unroll
        for (int j = 0; j < 4; j++) {
            float rs = (pv[0][j] + pv[1][j]) + (pv[2][j] + pv[3][j]);
            rs += __shfl_xor(rs, 1, 64);
            rs += __shfl_xor(rs, 2, 64);
            rs += __shfl_xor(rs, 4, 64);
            rs += __shfl_xor(rs, 8, 64);
            sm[j] += rs;
        }

        // P -> LDS (wave-private re-fragmentation for PV A-operand)
#pragma unroll
        for (int nf = 0; nf < 4; nf++)
#pragma unroll
            for (int j = 0; j < 4; j++)
                *(ushort*)swzp(Ps, lg * 4 + j, (nf * 16 + lr) * 2) = f2b(pv[nf][j]);

        bf16x8 pa0 = *(const bf16x8*)swzpc(Ps, lr, lg * 16);
        bf16x8 pa1 = *(const bf16x8*)swzpc(Ps, lr, 64 + lg * 16);
        __builtin_amdgcn_s_setprio(1);
#pragma unroll
        for (int nf = 0; nf < 4; nf++) {
            bf16x8 v0 = *(const bf16x8*)swzpc(Vs, nf * 16 + lr, lg * 16);
            bf16x8 v1 = *(const bf16x8*)swzpc(Vs, nf * 16 + lr, 64 + lg * 16);
            accO[nf] = __builtin_amdgcn_mfma_f32_16x16x32_bf16(pa0, v0, accO[nf], 0, 0, 0);
            accO[nf] = __builtin_amdgcn_mfma_f32_16x16x32_bf16(pa1, v1, accO[nf], 0, 0, 0);
        }
        __builtin_amdgcn_s_setprio(0);
    }

    // 4-way merge: each wave publishes (O, sum); combine cooperatively.
    __syncthreads();   // all waves done with Ks/Vs/Ps
#pragma unroll
    for (int nf = 0; nf < 4; nf++)
#pragma unroll
        for (int j = 0; j < 4; j++)
            Om[((size_t)wv * 16 + lg * 4 + j) * 64 + nf * 16 + lr] = accO[nf][j];
    if (lr == 0) {
#pragma unroll
        for (int j = 0; j < 4; j++)
            Ss[wv * 16 + lg * 4 + j] = sm[j];
    }
    __syncthreads();
    ushort* obase = ctx + (size_t)(b * SEQ + qt * 16) * DM + h * HD;
#pragma unroll
    for (int i = 0; i < 4; i++) {
        int e = i * 256 + tid;           // 0..1023
        int q = e >> 6, d = e & 63;
        float o = Om[e] + Om[1024 + e] + Om[2048 + e] + Om[3072 + e];
        float s = Ss[q] + Ss[16 + q] + Ss[32 + q] + Ss[48 + q];
        obase[(size_t)q * DM + d] = f2b(o / s);
    }
}

// ---------------------------------------------------------------- launch
extern "C" void kernel_launch(void* const* d_in, const int* in_sizes, int n_in,
                              void* d_out, int out_size, void* d_ws, size_t ws_size,
                              hipStream_t stream) {
    const int*   tokens  = (const int*)d_in[0];
    const float* tok_emb = (const float*)d_in[1];
    const float* pos_emb = (const float*)d_in[2];
    const float* ln1_s   = (const float*)d_in[3];
    const float* ln1_b   = (const float*)d_in[4];
    const float* Wq      = (const float*)d_in[5];
    const float* bq      = (const float*)d_in[6];
    const float* Wk      = (const float*)d_in[7];
    const float* bk      = (const float*)d_in[8];
    const float* Wv      = (const float*)d_in[9];
    const float* bv      = (const float*)d_in[10];
    const float* Wo      = (const float*)d_in[11];
    const float* bo      = (const float*)d_in[12];
    const float* ln2_s   = (const float*)d_in[13];
    const float* ln2_b   = (const float*)d_in[14];
    const float* W1      = (const float*)d_in[15];
    const float* b1      = (const float*)d_in[16];
    const float* W2      = (const float*)d_in[17];
    const float* b2      = (const float*)d_in[18];
    const float* W_out   = (const float*)d_in[19];
    const float* b_out   = (const float*)d_in[20];

    char* ws = (char*)d_ws;
    size_t off = 0;
    auto alloc = [&](size_t bytes) { size_t o = off; off = (off + bytes + 255) & ~(size_t)255; return o; };

    float*  x    = (float*)(ws + alloc((size_t)MT * DM * 4));
    ushort* x2b  = (ushort*)(ws + alloc((size_t)MT * DM * 2));
    ushort* qkvb = (ushort*)(ws + alloc((size_t)MT * QKV * 2));
    ushort* cb   = (ushort*)(ws + alloc((size_t)MT * DM * 2));
    ushort* hb   = (ushort*)(ws + alloc((size_t)MT * FF * 2));
    ushort* xb   = (ushort*)(ws + alloc((size_t)MT * DM * 2));
    ushort* vtb  = (ushort*)(ws + alloc((size_t)BATCH * NH * HD * SEQ * 2));
    float*  bqkv = (float*)(ws + alloc((size_t)NL * QKV * 4));

    size_t szQkvT = (size_t)NL * QKV * DM;
    size_t szWoT  = (size_t)NL * DM * DM;
    size_t szW1T  = (size_t)NL * FF * DM;
    size_t szW2T  = (size_t)NL * DM * FF;
    size_t szWoutT= (size_t)NV * DM;

    size_t actEnd = off;
    size_t fullNeed = actEnd + 2 * (szQkvT + szWoT + szW1T + szW2T + szWoutT) + 5 * 256;
    bool full = (fullNeed <= ws_size);

    ushort *WqkvT, *WoT, *W1T, *W2T, *WoutT;
    if (full) {
        WqkvT = (ushort*)(ws + alloc(szQkvT * 2));
        WoT   = (ushort*)(ws + alloc(szWoT * 2));
        W1T   = (ushort*)(ws + alloc(szW1T * 2));
        W2T   = (ushort*)(ws + alloc(szW2T * 2));
        WoutT = (ushort*)(ws + alloc(szWoutT * 2));
    } else {
        size_t layerElems = (size_t)QKV * DM + (size_t)DM * DM + 2 * (size_t)FF * DM;
        size_t regionElems = layerElems > szWoutT ? layerElems : szWoutT;
        ushort* region = (ushort*)(ws + alloc(regionElems * 2));
        WqkvT = region;
        WoT   = WqkvT + (size_t)QKV * DM;
        W1T   = WoT + (size_t)DM * DM;
        W2T   = W1T + (size_t)FF * DM;
        WoutT = region;
    }

    biaspack_kernel<<<(NL * QKV + 255) / 256, 256, 0, stream>>>(bq, bk, bv, bqkv);
    embed_kernel<<<MT, 256, 0, stream>>>(tokens, tok_emb, pos_emb, x);

    if (full) {
        dim3 gD(DM / 64, DM / 128, NL);
        wconv_kernel<<<gD, 256, 0, stream>>>(Wq, WqkvT, DM, DM, (size_t)DM * DM, (size_t)QKV * DM, 0);
        wconv_kernel<<<gD, 256, 0, stream>>>(Wk, WqkvT, DM, DM, (size_t)DM * DM, (size_t)QKV * DM, DM);
        wconv_kernel<<<gD, 256, 0, stream>>>(Wv, WqkvT, DM, DM, (size_t)DM * DM, (size_t)QKV * DM, 2 * DM);
        wconv_kernel<<<gD, 256, 0, stream>>>(Wo, WoT, DM, DM, (size_t)DM * DM, (size_t)DM * DM, 0);
        dim3 g1(FF / 64, DM / 128, NL);
        wconv_kernel<<<g1, 256, 0, stream>>>(W1, W1T, DM, FF, (size_t)DM * FF, (size_t)FF * DM, 0);
        dim3 g2(DM / 64, FF / 128, NL);
        wconv_kernel<<<g2, 256, 0, stream>>>(W2, W2T, FF, DM, (size_t)FF * DM, (size_t)DM * FF, 0);
        dim3 go(NV / 64, DM / 128, 1);
        wconv_kernel<<<go, 256, 0, stream>>>(W_out, WoutT, DM, NV, 0, 0, 0);
    }

    for (int l = 0; l < NL; l++) {
        ushort* wqkv = WqkvT + (full ? (size_t)l * QKV * DM : 0);
        ushort* wo   = WoT   + (full ? (size_t)l * DM * DM  : 0);
        ushort* w1   = W1T   + (full ? (size_t)l * FF * DM  : 0);
        ushort* w2   = W2T   + (full ? (size_t)l * DM * FF  : 0);
        if (!full) {
            dim3 gD(DM / 64, DM / 128, 1);
            wconv_kernel<<<gD, 256, 0, stream>>>(Wq + (size_t)l * DM * DM, wqkv, DM, DM, 0, 0, 0);
            wconv_kernel<<<gD, 256, 0, stream>>>(Wk + (size_t)l * DM * DM, wqkv, DM, DM, 0, 0, DM);
            wconv_kernel<<<gD, 256, 0, stream>>>(Wv + (size_t)l * DM * DM, wqkv, DM, DM, 0, 0, 2 * DM);
            wconv_kernel<<<gD, 256, 0, stream>>>(Wo + (size_t)l * DM * DM, wo, DM, DM, 0, 0, 0);
            dim3 g1(FF / 64, DM / 128, 1);
            wconv_kernel<<<g1, 256, 0, stream>>>(W1 + (size_t)l * DM * FF, w1, DM, FF, 0, 0, 0);
            dim3 g2(DM / 64, FF / 128, 1);
            wconv_kernel<<<g2, 256, 0, stream>>>(W2 + (size_t)l * FF * DM, w2, FF, DM, 0, 0, 0);
        }

        ln_kernel<<<MT, 256, 0, stream>>>(x, ln1_s + l * DM, ln1_b + l * DM, x2b);

        // QKV GEMM (64x64, KSTEP=64); V n-tiles written transposed to vtb
        gemm_qkv<<<dim3(QKV / 64, MT / 64), 256, 0, stream>>>(
            x2b, wqkv, bqkv + (size_t)l * QKV, qkvb, vtb, MT, QKV, DM);

        fattn_kernel<<<dim3(SEQ / 16, NH, BATCH), 256, 0, stream>>>(qkvb, vtb, cb);

        // x += ctx @ Wo + bo   (split-K x3, atomic accumulate into x)
        gemm_wo<<<dim3(DM / 64, MT / 64, 3), 256, 0, stream>>>(
            cb, wo, bo + (size_t)l * DM, x, MT, DM, DM);

        ln_kernel<<<MT, 256, 0, stream>>>(x, ln2_s + l * DM, ln2_b + l * DM, x2b);

        // W1 GEMM (64x64, KSTEP=64)
        gemm_w1<<<dim3(FF / 64, MT / 64), 256, 0, stream>>>(
            x2b, w1, b1 + (size_t)l * FF, hb, MT, FF, DM);

        // x += h @ W2 + b2   (split-K x3, atomic accumulate into x)
        gemm_w2<<<dim3(DM / 64, MT / 64, 3), 256, 0, stream>>>(
            hb, w2, b2 + (size_t)l * DM, x, MT, DM, FF);
    }

    if (!full) {
        dim3 go(NV / 64, DM / 128, 1);
        wconv_kernel<<<go, 256, 0, stream>>>(W_out, WoutT, DM, NV, 0, 0, 0);
    }
    cvt_kernel<<<(MT * DM + 255) / 256, 256, 0, stream>>>(x, xb, MT * DM);

    // logits: 128x256 tile, 8 waves (2x4), KSTEP=32 NBUF=3 (72KB -> 2 blk/CU)
    gemm_logits<<<dim3(NV / 256, MT / 128), 512, 0, stream>>>(
        xb, WoutT, b_out, (float*)d_out, MT, NV, DM);
}

// Round 14
// 1115.742 us; speedup vs baseline: 1.0589x; 1.0589x over previous
//
#include <hip/hip_runtime.h>
#include <hip/hip_bf16.h>
#include <math.h>

// GPT-1 forward: B=2 S=512 D=768 H=12 DFF=3072 L=12 V=32000
constexpr int BATCH = 2;
constexpr int SEQ   = 512;
constexpr int DM    = 768;
constexpr int NH    = 12;
constexpr int FF    = 3072;
constexpr int NL    = 12;
constexpr int NV    = 32000;
constexpr int HD    = 64;
constexpr int MT    = BATCH * SEQ; // 1024 token rows
constexpr int QKV   = 3 * DM;      // 2304

typedef __attribute__((ext_vector_type(8))) short bf16x8;
typedef __attribute__((ext_vector_type(4))) float f32x4;

__device__ __forceinline__ float b2f(ushort u) {
    return __uint_as_float(((unsigned)u) << 16);
}
__device__ __forceinline__ ushort f2b(float f) {
    __hip_bfloat16 h = __float2bfloat16(f);
    return *reinterpret_cast<ushort*>(&h);
}

template<int N>
__device__ __forceinline__ void waitcnt_vm() {
    if constexpr (N == 0) asm volatile("s_waitcnt vmcnt(0)" ::: "memory");
    else if constexpr (N == 2) asm volatile("s_waitcnt vmcnt(2)" ::: "memory");
    else if constexpr (N == 3) asm volatile("s_waitcnt vmcnt(3)" ::: "memory");
    else if constexpr (N == 4) asm volatile("s_waitcnt vmcnt(4)" ::: "memory");
    else if constexpr (N == 6) asm volatile("s_waitcnt vmcnt(6)" ::: "memory");
    else if constexpr (N == 8) asm volatile("s_waitcnt vmcnt(8)" ::: "memory");
}

// ---------------------------------------------------------------- embedding
__global__ void embed_kernel(const int* __restrict__ tokens,
                             const float* __restrict__ tok_emb,
                             const float* __restrict__ pos_emb,
                             float* __restrict__ x) {
    int m = blockIdx.x;
    int s = m % SEQ;
    int t = tokens[m];
    const float* te = tok_emb + (size_t)t * DM;
    const float* pe = pos_emb + (size_t)s * DM;
    float* row = x + (size_t)m * DM;
    for (int d = threadIdx.x; d < DM; d += blockDim.x)
        row[d] = te[d] + pe[d];
}

// ------------------------------------------------- weight convert+transpose
// in: f32 [l][K][N]; out: bf16 [l][N][K]. Tile 64 n x 128 k.
__global__ __launch_bounds__(256) void wconv_kernel(
        const float* __restrict__ W, ushort* __restrict__ out,
        int K, int N, size_t inLS, size_t outLS, int nOff) {
    int l  = blockIdx.z;
    int n0 = blockIdx.x * 64;
    int k0 = blockIdx.y * 128;
    int tid = threadIdx.x;
    __shared__ float t[2][64][65];   // [k-half][k%64][n]
    const float* src = W + (size_t)l * inLS + (size_t)k0 * N + n0;
    int r  = tid >> 4;           // 0..15
    int c4 = (tid & 15) * 4;     // 0..60
#pragma unroll
    for (int i = 0; i < 8; i++) {
        int krow = i * 16 + r;           // 0..127
        float4 v = *(const float4*)(src + (size_t)krow * N + c4);
        float* dstl = &t[krow >> 6][krow & 63][c4];
        dstl[0] = v.x; dstl[1] = v.y; dstl[2] = v.z; dstl[3] = v.w;
    }
    __syncthreads();
    ushort* dst = out + (size_t)l * outLS;
    int kk = (tid & 15) * 8;     // 0..120 (lane's 8-elem k chunk)
    int h  = kk >> 6;            // half
    int kb = kk & 63;
#pragma unroll
    for (int j = 0; j < 4; j++) {
        int n = j * 16 + (tid >> 4);     // 0..63
        ushort o[8];
#pragma unroll
        for (int m = 0; m < 8; m++) o[m] = f2b(t[h][kb + m][n]);
        *(ushort4*)(dst + (size_t)(nOff + n0 + n) * K + k0 + kk)     = *(ushort4*)&o[0];
        *(ushort4*)(dst + (size_t)(nOff + n0 + n) * K + k0 + kk + 4) = *(ushort4*)&o[4];
    }
}

// ---------------------------------------------------------------- bias pack
__global__ void biaspack_kernel(const float* __restrict__ bq,
                                const float* __restrict__ bk,
                                const float* __restrict__ bv,
                                float* __restrict__ bqkv) {
    int idx = blockIdx.x * 256 + threadIdx.x;
    if (idx >= NL * QKV) return;
    int l = idx / QKV, c = idx % QKV;
    float v;
    if (c < DM)            v = bq[l * DM + c];
    else if (c < 2 * DM)   v = bk[l * DM + c - DM];
    else                   v = bv[l * DM + c - 2 * DM];
    bqkv[idx] = v;
}

// --------------------------------------------------------- fold + f32->bf16
// xb = bf16(x + P0 + P1 + P2)   (final-layer w2 partial fold)
__global__ void fold_kernel(const float* __restrict__ x, const float* __restrict__ pb,
                            ushort* __restrict__ out, int n) {
    int i = blockIdx.x * 256 + threadIdx.x;
    if (i < n) out[i] = f2b(x[i] + pb[i] + pb[n + i] + pb[2 * n + i]);
}

// ---------------------------------------------------------------- layernorm
// If pb != null: xs = x + pb[0] + pb[MT*DM] + pb[2*MT*DM] (split-K partial
// fold), write xs back to xw, then y = LN(xs)*sc + bi. Else plain LN(x).
__global__ __launch_bounds__(256) void ln_kernel(const float* __restrict__ x,
                                                 const float* __restrict__ pb,
                                                 const float* __restrict__ sc,
                                                 const float* __restrict__ bi,
                                                 ushort* __restrict__ y,
                                                 float* __restrict__ xw) {
    int m = blockIdx.x;
    int t = threadIdx.x;
    const float* row = x + (size_t)m * DM;
    float vals[3];
    float s0 = 0.f, s1 = 0.f;
#pragma unroll
    for (int i = 0; i < 3; i++) {
        int d = t + 256 * i;
        float v = row[d];
        if (pb) {
            size_t idx = (size_t)m * DM + d;
            v += pb[idx] + pb[(size_t)MT * DM + idx] + pb[2 * (size_t)MT * DM + idx];
        }
        vals[i] = v;
        s0 += v;
        s1 += v * v;
    }
    if (pb) {
        float* wrow = xw + (size_t)m * DM;
#pragma unroll
        for (int i = 0; i < 3; i++) wrow[t + 256 * i] = vals[i];
    }
#pragma unroll
    for (int off = 32; off >= 1; off >>= 1) {
        s0 += __shfl_down(s0, off, 64);
        s1 += __shfl_down(s1, off, 64);
    }
    __shared__ float r0[4], r1[4];
    __shared__ float mu_s, rs_s;
    int wid = t >> 6, lane = t & 63;
    if (lane == 0) { r0[wid] = s0; r1[wid] = s1; }
    __syncthreads();
    if (t == 0) {
        float a = r0[0] + r0[1] + r0[2] + r0[3];
        float q = r1[0] + r1[1] + r1[2] + r1[3];
        float mu  = a / DM;
        float var = q / DM - mu * mu;
        mu_s = mu;
        rs_s = rsqrtf(var + 1e-5f);
    }
    __syncthreads();
    float mu = mu_s, rs = rs_s;
    ushort* orow = y + (size_t)m * DM;
#pragma unroll
    for (int i = 0; i < 3; i++) {
        int d = t + 256 * i;
        orow[d] = f2b((vals[i] - mu) * rs * sc[d] + bi[d]);
    }
}

// ---------------------------------------------------------------- MFMA GEMM
__device__ __forceinline__ void gload_lds16(const void* g, void* l) {
    __builtin_amdgcn_global_load_lds(
        (const __attribute__((address_space(1))) void*)g,
        (__attribute__((address_space(3))) void*)l, 16, 0, 0);
}

template<int BM, int BN, int WM, int WN, int KSTEP, int NBUF, int SPLITK, int ACT,
         bool RES, bool WF32, bool WBF16, bool VT, bool PART>
__device__ __forceinline__ void gemm_body(
        const ushort* __restrict__ A, const ushort* __restrict__ BT,
        const float* __restrict__ bias, const float* __restrict__ res,
        float* __restrict__ Cf, ushort* __restrict__ Cb, ushort* __restrict__ Vt,
        int M, int N, int K) {
    constexpr int THREADS = WM * WN * 64;
    constexpr int ROWS    = BM + BN;
    constexpr int SEGS    = KSTEP / 8;           // 16B segments per row
    constexpr int SEGSH   = (KSTEP == 32) ? 2 : 3;
    constexpr int RND     = ROWS * KSTEP / (THREADS * 8);
    constexpr int MR      = BM / WM / 16;
    constexpr int NR      = BN / WN / 16;
    constexpr int KCH     = KSTEP / 32;          // mfma k-subtiles per step
    constexpr int STRIDE  = ROWS * KSTEP;        // ushorts per buffer
    __shared__ ushort S_lds[NBUF * STRIDE];
    int tid = threadIdx.x;
    int il = tid & 63, wv = tid >> 6;

    // bijective XCD-chunked swizzle
    int p   = blockIdx.x + gridDim.x * blockIdx.y;
    int nwg = gridDim.x * gridDim.y;
    int q8  = nwg >> 3, r8 = nwg & 7;
    int xcd = p & 7, k8 = p >> 3;
    int orig = (xcd < r8 ? xcd * (q8 + 1) : r8 * (q8 + 1) + (xcd - r8) * q8) + k8;
    int bx = orig / gridDim.y;       // n-tile  (y-major)
    int by = orig % gridDim.y;       // m-tile
    int bm = by * BM, bn = bx * BN;

    int kLen  = K / SPLITK;
    int kBase = blockIdx.z * kLen;

    auto swz = [](int row) -> int {
        return (KSTEP == 32) ? ((row >> 1) & 3) : (row & 7);
    };

    const ushort* src[RND];
    int dstOff[RND];
#pragma unroll
    for (int r = 0; r < RND; r++) {
        int f = r * THREADS + tid;
        int row = f >> SEGSH, seg = f & (SEGS - 1);
        int lseg = seg ^ swz(row);
        src[r] = (row < BM ? A + (size_t)(bm + row) * K
                           : BT + (size_t)(bn + row - BM) * K) + kBase + lseg * 8;
        dstOff[r] = (r * THREADS + wv * 64) * 8;
    }

    int wm = wv / WN, wn = wv % WN;
    int lr = il & 15;
    int lg = il >> 4;
    int swzR = swz(lr);
    f32x4 acc[MR][NR] = {};

    int nt = kLen / KSTEP;

    // prologue: stage tiles 0..NBUF-2
#pragma unroll
    for (int b = 0; b < NBUF - 1; b++)
#pragma unroll
        for (int r = 0; r < RND; r++)
            gload_lds16(src[r] + b * KSTEP, &S_lds[b * STRIDE + dstOff[r]]);
    waitcnt_vm<RND * (NBUF - 2)>();
    __builtin_amdgcn_s_barrier();

    int cur = 0;
    for (int t = 0; t < nt; ++t) {
        if (t + NBUF - 1 < nt) {
            int sb = cur + NBUF - 1; if (sb >= NBUF) sb -= NBUF;
            int kofs = (t + NBUF - 1) * KSTEP;
            ushort* Bp = &S_lds[sb * STRIDE];
#pragma unroll
            for (int r = 0; r < RND; r++) gload_lds16(src[r] + kofs, &Bp[dstOff[r]]);
        }

        const ushort* base = &S_lds[cur * STRIDE];
        bf16x8 af[KCH][MR], bfr[KCH][NR];
#pragma unroll
        for (int kk = 0; kk < KCH; kk++) {
            int phys = ((kk * 4 + lg) ^ swzR) * 8;
#pragma unroll
            for (int i = 0; i < MR; i++)
                af[kk][i] = *(const bf16x8*)&base[(wm * (BM / WM) + i * 16 + lr) * KSTEP + phys];
#pragma unroll
            for (int i = 0; i < NR; i++)
                bfr[kk][i] = *(const bf16x8*)&base[(BM + wn * (BN / WN) + i * 16 + lr) * KSTEP + phys];
        }
        __builtin_amdgcn_s_setprio(1);
#pragma unroll
        for (int kk = 0; kk < KCH; kk++)
#pragma unroll
            for (int mi = 0; mi < MR; mi++)
#pragma unroll
                for (int ni = 0; ni < NR; ni++)
                    acc[mi][ni] = __builtin_amdgcn_mfma_f32_16x16x32_bf16(
                        af[kk][mi], bfr[kk][ni], acc[mi][ni], 0, 0, 0);
        __builtin_amdgcn_s_setprio(0);

        if (t + 1 < nt) {
            int k = nt - t - 2;
            if (k > NBUF - 2) k = NBUF - 2;
            switch (k) {
                case 0:  waitcnt_vm<0>(); break;
                case 1:  waitcnt_vm<RND>(); break;
                default: waitcnt_vm<2 * RND>(); break;
            }
            __builtin_amdgcn_s_barrier();
        }
        cur = (cur + 1 == NBUF) ? 0 : cur + 1;
    }

    bool addBias = bias && (SPLITK == 1 || blockIdx.z == 0);
    size_t partOfs = PART ? (size_t)blockIdx.z * M * N : 0;
#pragma unroll
    for (int mi = 0; mi < MR; mi++) {
        int row0 = bm + wm * (BM / WM) + mi * 16 + (il >> 4) * 4;
#pragma unroll
        for (int ni = 0; ni < NR; ni++) {
            int col = bn + wn * (BN / WN) + ni * 16 + (il & 15);
            float bv = addBias ? bias[col] : 0.f;
#pragma unroll
            for (int j = 0; j < 4; j++) {
                int r = row0 + j;
                float v = acc[mi][ni][j] + bv;
                if (ACT == 1) v = 0.5f * v * (1.0f + erff(v * 0.70710678118654752f));
                if (RES) v += res[(size_t)r * N + col];
                if (PART) Cf[partOfs + (size_t)r * N + col] = v;
                else if (WF32) Cf[(size_t)r * N + col] = v;
                if (WBF16) {
                    if (VT && bn >= 2 * DM) {
                        int d  = col - 2 * DM;
                        int hh = d >> 6, dd = d & 63;
                        int bb = r >> 9, s = r & (SEQ - 1);
                        Vt[((size_t)(bb * NH + hh) * HD + dd) * SEQ + s] = f2b(v);
                    } else {
                        Cb[(size_t)r * N + col] = f2b(v);
                    }
                }
            }
        }
    }
}

// named wrappers; layer GEMMs: 64x64, KSTEP=64, NBUF=3 (proven R12).
// wo/w2: split-K x3 partial-plane writes (plain stores; fold in next ln).
// logits: proven 256x256 KSTEP=32 NBUF=4.
__global__ __launch_bounds__(256) void gemm_qkv(
        const ushort* A, const ushort* BT, const float* bias,
        ushort* Cb, ushort* Vt, int M, int N, int K) {
    gemm_body<64, 64, 2, 2, 64, 3, 1, 0, false, false, true, true, false>(
        A, BT, bias, nullptr, nullptr, Cb, Vt, M, N, K);
}
__global__ __launch_bounds__(256) void gemm_wo(
        const ushort* A, const ushort* BT, const float* bias,
        float* Pf, int M, int N, int K) {
    gemm_body<64, 64, 2, 2, 64, 3, 3, 0, false, false, false, false, true>(
        A, BT, bias, nullptr, Pf, nullptr, nullptr, M, N, K);
}
__global__ __launch_bounds__(256) void gemm_w1(
        const ushort* A, const ushort* BT, const float* bias,
        ushort* Cb, int M, int N, int K) {
    gemm_body<64, 64, 2, 2, 64, 3, 1, 1, false, false, true, false, false>(
        A, BT, bias, nullptr, nullptr, Cb, nullptr, M, N, K);
}
__global__ __launch_bounds__(256) void gemm_w2(
        const ushort* A, const ushort* BT, const float* bias,
        float* Pf, int M, int N, int K) {
    gemm_body<64, 64, 2, 2, 64, 3, 3, 0, false, false, false, false, true>(
        A, BT, bias, nullptr, Pf, nullptr, nullptr, M, N, K);
}
__global__ __launch_bounds__(512) void gemm_logits(
        const ushort* A, const ushort* BT, const float* bias,
        float* Cf, int M, int N, int K) {
    gemm_body<256, 256, 2, 4, 32, 4, 1, 0, false, true, false, false, false>(
        A, BT, bias, nullptr, Cf, nullptr, nullptr, M, N, K);
}

// ---------------------------------------------------------------- flash attn
// Proven R12 structure: 32 q-rows, 4 waves, 2-way key-split, staged LDS with
// register prefetch of next tile. Fixed-shift softmax.
__device__ __forceinline__ char* swzp(void* base, int row, int colByte) {
    return (char*)base + ((row * 128 + colByte) ^ ((row & 7) << 4));
}
__device__ __forceinline__ const char* swzpc(const void* base, int row, int colByte) {
    return (const char*)base + ((row * 128 + colByte) ^ ((row & 7) << 4));
}

__global__ __launch_bounds__(256) void fattn_kernel(
        const ushort* __restrict__ qkv, const ushort* __restrict__ vt,
        ushort* __restrict__ ctx) {
    int qt = blockIdx.x;   // 0..15
    int h  = blockIdx.y;
    int b  = blockIdx.z;
    int tid = threadIdx.x;
    int il = tid & 63, wv = tid >> 6;
    int qsub = wv & 1, grp = wv >> 1;

    __shared__ __align__(16) char smem[41 * 1024];
    ushort* Ks = (ushort*)(smem + grp * 8192);
    ushort* Vs = (ushort*)(smem + 16384 + grp * 8192);
    ushort* Ps = (ushort*)(smem + 32768 + wv * 2048);
    float*  Om = (float*)smem;                   // merge alias (8KB)
    float*  Ss = (float*)(smem + 16384);

    int bh = b * NH + h;
    const ushort* kbase = qkv + (size_t)b * SEQ * QKV + DM + h * HD;
    const ushort* vbase = vt + (size_t)bh * HD * SEQ;

    int lr = il & 15, lg = il >> 4;
    int qrow = qt * 32 + qsub * 16 + lr;
    const ushort* qptr = qkv + (size_t)(b * SEQ + qrow) * QKV + h * HD + lg * 8;
    bf16x8 qf0 = *(const bf16x8*)qptr;
    bf16x8 qf1 = *(const bf16x8*)(qptr + 32);

    f32x4 accO[4] = {};
    float sm[4] = {0.f, 0.f, 0.f, 0.f};

    int lig  = qsub * 64 + il;       // 0..127 within key-group
    int srow = lig >> 3;             // 0..15
    int sseg = (lig & 7) * 8;        // 0..56

    // preload tile 0 into registers
    bf16x8 kreg[4], vreg[4];
    {
        int k0 = grp * 256;
#pragma unroll
        for (int r = 0; r < 4; r++) {
            int row = r * 16 + srow;
            kreg[r] = *(const bf16x8*)(kbase + (size_t)(k0 + row) * QKV + sseg);
            vreg[r] = *(const bf16x8*)(vbase + (size_t)row * SEQ + k0 + sseg);
        }
    }

    for (int kt = 0; kt < 4; kt++) {
        __syncthreads();   // prev iter's LDS readers done
#pragma unroll
        for (int r = 0; r < 4; r++) {
            int row = r * 16 + srow;
            *(bf16x8*)swzp(Ks, row, sseg * 2) = kreg[r];
            *(bf16x8*)swzp(Vs, row, sseg * 2) = vreg[r];
        }
        __syncthreads();   // tiles visible

        // prefetch next tile into registers (hides under compute below)
        if (kt < 3) {
            int k0n = grp * 256 + (kt + 1) * 64;
#pragma unroll
            for (int r = 0; r < 4; r++) {
                int row = r * 16 + srow;
                kreg[r] = *(const bf16x8*)(kbase + (size_t)(k0n + row) * QKV + sseg);
                vreg[r] = *(const bf16x8*)(vbase + (size_t)row * SEQ + k0n + sseg);
            }
        }

        // QK^T: S[q 16][key 64]
        f32x4 accS[4] = {};
        __builtin_amdgcn_s_setprio(1);
#pragma unroll
        for (int nf = 0; nf < 4; nf++) {
            bf16x8 b0 = *(const bf16x8*)swzpc(Ks, nf * 16 + lr, lg * 16);
            bf16x8 b1 = *(const bf16x8*)swzpc(Ks, nf * 16 + lr, 64 + lg * 16);
            accS[nf] = __builtin_amdgcn_mfma_f32_16x16x32_bf16(qf0, b0, accS[nf], 0, 0, 0);
            accS[nf] = __builtin_amdgcn_mfma_f32_16x16x32_bf16(qf1, b1, accS[nf], 0, 0, 0);
        }
        __builtin_amdgcn_s_setprio(0);

        // P = exp(s*0.125 - 8); row-sum only (no max tracking)
        float pv[4][4];
#pragma unroll
        for (int nf = 0; nf < 4; nf++)
#pragma unroll
            for (int j = 0; j < 4; j++)
                pv[nf][j] = __expf(fmaf(accS[nf][j], 0.125f, -8.0f));
#pragma unroll
        for (int j = 0; j < 4; j++) {
            float rs = (pv[0][j] + pv[1][j]) + (pv[2][j] + pv[3][j]);
            rs += __shfl_xor(rs, 1, 64);
            rs += __shfl_xor(rs, 2, 64);
            rs += __shfl_xor(rs, 4, 64);
            rs += __shfl_xor(rs, 8, 64);
            sm[j] += rs;
        }

        // P -> LDS (wave-private 16-row tile; re-fragment for PV A-operand)
#pragma unroll
        for (int nf = 0; nf < 4; nf++)
#pragma unroll
            for (int j = 0; j < 4; j++)
                *(ushort*)swzp(Ps, lg * 4 + j, (nf * 16 + lr) * 2) = f2b(pv[nf][j]);

        bf16x8 pa0 = *(const bf16x8*)swzpc(Ps, lr, lg * 16);
        bf16x8 pa1 = *(const bf16x8*)swzpc(Ps, lr, 64 + lg * 16);
        __builtin_amdgcn_s_setprio(1);
#pragma unroll
        for (int nf = 0; nf < 4; nf++) {
            bf16x8 v0 = *(const bf16x8*)swzpc(Vs, nf * 16 + lr, lg * 16);
            bf16x8 v1 = *(const bf16x8*)swzpc(Vs, nf * 16 + lr, 64 + lg * 16);
            accO[nf] = __builtin_amdgcn_mfma_f32_16x16x32_bf16(pa0, v0, accO[nf], 0, 0, 0);
            accO[nf] = __builtin_amdgcn_mfma_f32_16x16x32_bf16(pa1, v1, accO[nf], 0, 0, 0);
        }
        __builtin_amdgcn_s_setprio(0);
    }

    // merge key-halves: plain sums
    __syncthreads();
    if (grp == 1) {
#pragma unroll
        for (int nf = 0; nf < 4; nf++)
#pragma unroll
            for (int j = 0; j < 4; j++)
                Om[(qsub * 16 + lg * 4 + j) * 64 + nf * 16 + lr] = accO[nf][j];
        if (lr == 0) {
#pragma unroll
            for (int j = 0; j < 4; j++)
                Ss[qsub * 16 + lg * 4 + j] = sm[j];
        }
    }
    __syncthreads();
    if (grp == 0) {
        ushort* obase = ctx + (size_t)(b * SEQ + qt * 32 + qsub * 16) * DM + h * HD;
#pragma unroll
        for (int j = 0; j < 4; j++) {
            int q = lg * 4 + j;
            float inv = 1.0f / (sm[j] + Ss[qsub * 16 + q]);
#pragma unroll
            for (int nf = 0; nf < 4; nf++) {
                int d = nf * 16 + lr;
                float o1 = Om[(qsub * 16 + q) * 64 + d];
                obase[(size_t)q * DM + d] = f2b((accO[nf][j] + o1) * inv);
            }
        }
    }
}

// ---------------------------------------------------------------- launch
extern "C" void kernel_launch(void* const* d_in, const int* in_sizes, int n_in,
                              void* d_out, int out_size, void* d_ws, size_t ws_size,
                              hipStream_t stream) {
    const int*   tokens  = (const int*)d_in[0];
    const float* tok_emb = (const float*)d_in[1];
    const float* pos_emb = (const float*)d_in[2];
    const float* ln1_s   = (const float*)d_in[3];
    const float* ln1_b   = (const float*)d_in[4];
    const float* Wq      = (const float*)d_in[5];
    const float* bq      = (const float*)d_in[6];
    const float* Wk      = (const float*)d_in[7];
    const float* bk      = (const float*)d_in[8];
    const float* Wv      = (const float*)d_in[9];
    const float* bv      = (const float*)d_in[10];
    const float* Wo      = (const float*)d_in[11];
    const float* bo      = (const float*)d_in[12];
    const float* ln2_s   = (const float*)d_in[13];
    const float* ln2_b   = (const float*)d_in[14];
    const float* W1      = (const float*)d_in[15];
    const float* b1      = (const float*)d_in[16];
    const float* W2      = (const float*)d_in[17];
    const float* b2      = (const float*)d_in[18];
    const float* W_out   = (const float*)d_in[19];
    const float* b_out   = (const float*)d_in[20];

    char* ws = (char*)d_ws;
    size_t off = 0;
    auto alloc = [&](size_t bytes) { size_t o = off; off = (off + bytes + 255) & ~(size_t)255; return o; };

    float*  x    = (float*)(ws + alloc((size_t)MT * DM * 4));
    float*  pbuf = (float*)(ws + alloc(3 * (size_t)MT * DM * 4));   // split-K partials
    ushort* x2b  = (ushort*)(ws + alloc((size_t)MT * DM * 2));
    ushort* qkvb = (ushort*)(ws + alloc((size_t)MT * QKV * 2));
    ushort* cb   = (ushort*)(ws + alloc((size_t)MT * DM * 2));
    ushort* hb   = (ushort*)(ws + alloc((size_t)MT * FF * 2));
    ushort* xb   = (ushort*)(ws + alloc((size_t)MT * DM * 2));
    ushort* vtb  = (ushort*)(ws + alloc((size_t)BATCH * NH * HD * SEQ * 2));
    float*  bqkv = (float*)(ws + alloc((size_t)NL * QKV * 4));

    size_t szQkvT = (size_t)NL * QKV * DM;
    size_t szWoT  = (size_t)NL * DM * DM;
    size_t szW1T  = (size_t)NL * FF * DM;
    size_t szW2T  = (size_t)NL * DM * FF;
    size_t szWoutT= (size_t)NV * DM;

    size_t actEnd = off;
    size_t fullNeed = actEnd + 2 * (szQkvT + szWoT + szW1T + szW2T + szWoutT) + 5 * 256;
    bool full = (fullNeed <= ws_size);

    ushort *WqkvT, *WoT, *W1T, *W2T, *WoutT;
    if (full) {
        WqkvT = (ushort*)(ws + alloc(szQkvT * 2));
        WoT   = (ushort*)(ws + alloc(szWoT * 2));
        W1T   = (ushort*)(ws + alloc(szW1T * 2));
        W2T   = (ushort*)(ws + alloc(szW2T * 2));
        WoutT = (ushort*)(ws + alloc(szWoutT * 2));
    } else {
        size_t layerElems = (size_t)QKV * DM + (size_t)DM * DM + 2 * (size_t)FF * DM;
        size_t regionElems = layerElems > szWoutT ? layerElems : szWoutT;
        ushort* region = (ushort*)(ws + alloc(regionElems * 2));
        WqkvT = region;
        WoT   = WqkvT + (size_t)QKV * DM;
        W1T   = WoT + (size_t)DM * DM;
        W2T   = W1T + (size_t)FF * DM;
        WoutT = region;
    }

    biaspack_kernel<<<(NL * QKV + 255) / 256, 256, 0, stream>>>(bq, bk, bv, bqkv);
    embed_kernel<<<MT, 256, 0, stream>>>(tokens, tok_emb, pos_emb, x);

    if (full) {
        dim3 gD(DM / 64, DM / 128, NL);
        wconv_kernel<<<gD, 256, 0, stream>>>(Wq, WqkvT, DM, DM, (size_t)DM * DM, (size_t)QKV * DM, 0);
        wconv_kernel<<<gD, 256, 0, stream>>>(Wk, WqkvT, DM, DM, (size_t)DM * DM, (size_t)QKV * DM, DM);
        wconv_kernel<<<gD, 256, 0, stream>>>(Wv, WqkvT, DM, DM, (size_t)DM * DM, (size_t)QKV * DM, 2 * DM);
        wconv_kernel<<<gD, 256, 0, stream>>>(Wo, WoT, DM, DM, (size_t)DM * DM, (size_t)DM * DM, 0);
        dim3 g1(FF / 64, DM / 128, NL);
        wconv_kernel<<<g1, 256, 0, stream>>>(W1, W1T, DM, FF, (size_t)DM * FF, (size_t)FF * DM, 0);
        dim3 g2(DM / 64, FF / 128, NL);
        wconv_kernel<<<g2, 256, 0, stream>>>(W2, W2T, FF, DM, (size_t)FF * DM, (size_t)DM * FF, 0);
        dim3 go(NV / 64, DM / 128, 1);
        wconv_kernel<<<go, 256, 0, stream>>>(W_out, WoutT, DM, NV, 0, 0, 0);
    }

    for (int l = 0; l < NL; l++) {
        ushort* wqkv = WqkvT + (full ? (size_t)l * QKV * DM : 0);
        ushort* wo   = WoT   + (full ? (size_t)l * DM * DM  : 0);
        ushort* w1   = W1T   + (full ? (size_t)l * FF * DM  : 0);
        ushort* w2   = W2T   + (full ? (size_t)l * DM * FF  : 0);
        if (!full) {
            dim3 gD(DM / 64, DM / 128, 1);
            wconv_kernel<<<gD, 256, 0, stream>>>(Wq + (size_t)l * DM * DM, wqkv, DM, DM, 0, 0, 0);
            wconv_kernel<<<gD, 256, 0, stream>>>(Wk + (size_t)l * DM * DM, wqkv, DM, DM, 0, 0, DM);
            wconv_kernel<<<gD, 256, 0, stream>>>(Wv + (size_t)l * DM * DM, wqkv, DM, DM, 0, 0, 2 * DM);
            wconv_kernel<<<gD, 256, 0, stream>>>(Wo + (size_t)l * DM * DM, wo, DM, DM, 0, 0, 0);
            dim3 g1(FF / 64, DM / 128, 1);
            wconv_kernel<<<g1, 256, 0, stream>>>(W1 + (size_t)l * DM * FF, w1, DM, FF, 0, 0, 0);
            dim3 g2(DM / 64, FF / 128, 1);
            wconv_kernel<<<g2, 256, 0, stream>>>(W2 + (size_t)l * FF * DM, w2, FF, DM, 0, 0, 0);
        }

        // ln1: l==0 plain; l>0 folds previous layer's w2 partials into x
        ln_kernel<<<MT, 256, 0, stream>>>(x, l == 0 ? nullptr : pbuf,
                                          ln1_s + l * DM, ln1_b + l * DM, x2b, x);

        // QKV GEMM (64x64, KSTEP=64); V n-tiles written transposed to vtb
        gemm_qkv<<<dim3(QKV / 64, MT / 64), 256, 0, stream>>>(
            x2b, wqkv, bqkv + (size_t)l * QKV, qkvb, vtb, MT, QKV, DM);

        fattn_kernel<<<dim3(SEQ / 32, NH, BATCH), 256, 0, stream>>>(qkvb, vtb, cb);

        // ctx @ Wo + bo -> 3 partial planes (plain stores, no atomics)
        gemm_wo<<<dim3(DM / 64, MT / 64, 3), 256, 0, stream>>>(
            cb, wo, bo + (size_t)l * DM, pbuf, MT, DM, DM);

        // ln2 folds wo partials: x += sum(P), then LN
        ln_kernel<<<MT, 256, 0, stream>>>(x, pbuf,
                                          ln2_s + l * DM, ln2_b + l * DM, x2b, x);

        // W1 GEMM (64x64, KSTEP=64)
        gemm_w1<<<dim3(FF / 64, MT / 64), 256, 0, stream>>>(
            x2b, w1, b1 + (size_t)l * FF, hb, MT, FF, DM);

        // h @ W2 + b2 -> 3 partial planes (folded by next ln1 / final fold)
        gemm_w2<<<dim3(DM / 64, MT / 64, 3), 256, 0, stream>>>(
            hb, w2, b2 + (size_t)l * DM, pbuf, MT, DM, FF);
    }

    if (!full) {
        dim3 go(NV / 64, DM / 128, 1);
        wconv_kernel<<<go, 256, 0, stream>>>(W_out, WoutT, DM, NV, 0, 0, 0);
    }
    // fold last w2 partials + convert to bf16
    fold_kernel<<<(MT * DM + 255) / 256, 256, 0, stream>>>(x, pbuf, xb, MT * DM);

    // logits: 256x256 tile, 8 waves (2x4), KSTEP=32 NBUF=4 (proven path)
    gemm_logits<<<dim3(NV / 256, MT / 256), 512, 0, stream>>>(
        xb, WoutT, b_out, (float*)d_out, MT, NV, DM);
}

// Round 15
// 1110.807 us; speedup vs baseline: 1.0636x; 1.0044x over previous
//
#include <hip/hip_runtime.h>
#include <hip/hip_bf16.h>
#include <math.h>

// GPT-1 forward: B=2 S=512 D=768 H=12 DFF=3072 L=12 V=32000
constexpr int BATCH = 2;
constexpr int SEQ   = 512;
constexpr int DM    = 768;
constexpr int NH    = 12;
constexpr int FF    = 3072;
constexpr int NL    = 12;
constexpr int NV    = 32000;
constexpr int HD    = 64;
constexpr int MT    = BATCH * SEQ; // 1024 token rows
constexpr int QKV   = 3 * DM;      // 2304
constexpr int SK    = 4;           // split-K planes for wo/w2

typedef __attribute__((ext_vector_type(8))) short bf16x8;
typedef __attribute__((ext_vector_type(4))) float f32x4;

__device__ __forceinline__ float b2f(ushort u) {
    return __uint_as_float(((unsigned)u) << 16);
}
__device__ __forceinline__ ushort f2b(float f) {
    __hip_bfloat16 h = __float2bfloat16(f);
    return *reinterpret_cast<ushort*>(&h);
}

template<int N>
__device__ __forceinline__ void waitcnt_vm() {
    if constexpr (N == 0) asm volatile("s_waitcnt vmcnt(0)" ::: "memory");
    else if constexpr (N == 2) asm volatile("s_waitcnt vmcnt(2)" ::: "memory");
    else if constexpr (N == 3) asm volatile("s_waitcnt vmcnt(3)" ::: "memory");
    else if constexpr (N == 4) asm volatile("s_waitcnt vmcnt(4)" ::: "memory");
    else if constexpr (N == 6) asm volatile("s_waitcnt vmcnt(6)" ::: "memory");
    else if constexpr (N == 8) asm volatile("s_waitcnt vmcnt(8)" ::: "memory");
}

// ---------------------------------------------------------------- embedding
__global__ void embed_kernel(const int* __restrict__ tokens,
                             const float* __restrict__ tok_emb,
                             const float* __restrict__ pos_emb,
                             float* __restrict__ x) {
    int m = blockIdx.x;
    int s = m % SEQ;
    int t = tokens[m];
    const float* te = tok_emb + (size_t)t * DM;
    const float* pe = pos_emb + (size_t)s * DM;
    float* row = x + (size_t)m * DM;
    for (int d = threadIdx.x; d < DM; d += blockDim.x)
        row[d] = te[d] + pe[d];
}

// ------------------------------------------------- weight convert+transpose
// in: f32 [l][K][N]; out: bf16 [l][N][K]. Tile 64 n x 128 k.
__global__ __launch_bounds__(256) void wconv_kernel(
        const float* __restrict__ W, ushort* __restrict__ out,
        int K, int N, size_t inLS, size_t outLS, int nOff) {
    int l  = blockIdx.z;
    int n0 = blockIdx.x * 64;
    int k0 = blockIdx.y * 128;
    int tid = threadIdx.x;
    __shared__ float t[2][64][65];   // [k-half][k%64][n]
    const float* src = W + (size_t)l * inLS + (size_t)k0 * N + n0;
    int r  = tid >> 4;           // 0..15
    int c4 = (tid & 15) * 4;     // 0..60
#pragma unroll
    for (int i = 0; i < 8; i++) {
        int krow = i * 16 + r;           // 0..127
        float4 v = *(const float4*)(src + (size_t)krow * N + c4);
        float* dstl = &t[krow >> 6][krow & 63][c4];
        dstl[0] = v.x; dstl[1] = v.y; dstl[2] = v.z; dstl[3] = v.w;
    }
    __syncthreads();
    ushort* dst = out + (size_t)l * outLS;
    int kk = (tid & 15) * 8;     // 0..120 (lane's 8-elem k chunk)
    int h  = kk >> 6;            // half
    int kb = kk & 63;
#pragma unroll
    for (int j = 0; j < 4; j++) {
        int n = j * 16 + (tid >> 4);     // 0..63
        ushort o[8];
#pragma unroll
        for (int m = 0; m < 8; m++) o[m] = f2b(t[h][kb + m][n]);
        *(ushort4*)(dst + (size_t)(nOff + n0 + n) * K + k0 + kk)     = *(ushort4*)&o[0];
        *(ushort4*)(dst + (size_t)(nOff + n0 + n) * K + k0 + kk + 4) = *(ushort4*)&o[4];
    }
}

// ---------------------------------------------------------------- bias pack
__global__ void biaspack_kernel(const float* __restrict__ bq,
                                const float* __restrict__ bk,
                                const float* __restrict__ bv,
                                float* __restrict__ bqkv) {
    int idx = blockIdx.x * 256 + threadIdx.x;
    if (idx >= NL * QKV) return;
    int l = idx / QKV, c = idx % QKV;
    float v;
    if (c < DM)            v = bq[l * DM + c];
    else if (c < 2 * DM)   v = bk[l * DM + c - DM];
    else                   v = bv[l * DM + c - 2 * DM];
    bqkv[idx] = v;
}

// --------------------------------------------------------- fold + f32->bf16
// xb = bf16(x + P0..P3)   (final-layer w2 partial fold)
__global__ void fold_kernel(const float* __restrict__ x, const float* __restrict__ pb,
                            ushort* __restrict__ out, int n) {
    int i = blockIdx.x * 256 + threadIdx.x;
    if (i < n) out[i] = f2b(x[i] + (pb[i] + pb[n + i]) + (pb[2 * n + i] + pb[3 * n + i]));
}

// ---------------------------------------------------------------- layernorm
// If pb != null: xs = x + sum of SK partial planes, write xs back to xw,
// then y = LN(xs)*sc + bi. Else plain LN(x).
__global__ __launch_bounds__(256) void ln_kernel(const float* __restrict__ x,
                                                 const float* __restrict__ pb,
                                                 const float* __restrict__ sc,
                                                 const float* __restrict__ bi,
                                                 ushort* __restrict__ y,
                                                 float* __restrict__ xw) {
    int m = blockIdx.x;
    int t = threadIdx.x;
    const float* row = x + (size_t)m * DM;
    float vals[3];
    float s0 = 0.f, s1 = 0.f;
#pragma unroll
    for (int i = 0; i < 3; i++) {
        int d = t + 256 * i;
        float v = row[d];
        if (pb) {
            size_t idx = (size_t)m * DM + d;
            v += (pb[idx] + pb[(size_t)MT * DM + idx])
               + (pb[2 * (size_t)MT * DM + idx] + pb[3 * (size_t)MT * DM + idx]);
        }
        vals[i] = v;
        s0 += v;
        s1 += v * v;
    }
    if (pb) {
        float* wrow = xw + (size_t)m * DM;
#pragma unroll
        for (int i = 0; i < 3; i++) wrow[t + 256 * i] = vals[i];
    }
#pragma unroll
    for (int off = 32; off >= 1; off >>= 1) {
        s0 += __shfl_down(s0, off, 64);
        s1 += __shfl_down(s1, off, 64);
    }
    __shared__ float r0[4], r1[4];
    __shared__ float mu_s, rs_s;
    int wid = t >> 6, lane = t & 63;
    if (lane == 0) { r0[wid] = s0; r1[wid] = s1; }
    __syncthreads();
    if (t == 0) {
        float a = r0[0] + r0[1] + r0[2] + r0[3];
        float q = r1[0] + r1[1] + r1[2] + r1[3];
        float mu  = a / DM;
        float var = q / DM - mu * mu;
        mu_s = mu;
        rs_s = rsqrtf(var + 1e-5f);
    }
    __syncthreads();
    float mu = mu_s, rs = rs_s;
    ushort* orow = y + (size_t)m * DM;
#pragma unroll
    for (int i = 0; i < 3; i++) {
        int d = t + 256 * i;
        orow[d] = f2b((vals[i] - mu) * rs * sc[d] + bi[d]);
    }
}

// ---------------------------------------------------------------- MFMA GEMM
__device__ __forceinline__ void gload_lds16(const void* g, void* l) {
    __builtin_amdgcn_global_load_lds(
        (const __attribute__((address_space(1))) void*)g,
        (__attribute__((address_space(3))) void*)l, 16, 0, 0);
}

template<int BM, int BN, int WM, int WN, int KSTEP, int NBUF, int SPLITK, int ACT,
         bool RES, bool WF32, bool WBF16, bool VT, bool PART>
__device__ __forceinline__ void gemm_body(
        const ushort* __restrict__ A, const ushort* __restrict__ BT,
        const float* __restrict__ bias, const float* __restrict__ res,
        float* __restrict__ Cf, ushort* __restrict__ Cb, ushort* __restrict__ Vt,
        int M, int N, int K) {
    constexpr int THREADS = WM * WN * 64;
    constexpr int ROWS    = BM + BN;
    constexpr int SEGS    = KSTEP / 8;           // 16B segments per row
    constexpr int SEGSH   = (KSTEP == 32) ? 2 : 3;
    constexpr int RND     = ROWS * KSTEP / (THREADS * 8);
    constexpr int MR      = BM / WM / 16;
    constexpr int NR      = BN / WN / 16;
    constexpr int KCH     = KSTEP / 32;          // mfma k-subtiles per step
    constexpr int STRIDE  = ROWS * KSTEP;        // ushorts per buffer
    __shared__ ushort S_lds[NBUF * STRIDE];
    int tid = threadIdx.x;
    int il = tid & 63, wv = tid >> 6;

    // bijective XCD-chunked swizzle
    int p   = blockIdx.x + gridDim.x * blockIdx.y;
    int nwg = gridDim.x * gridDim.y;
    int q8  = nwg >> 3, r8 = nwg & 7;
    int xcd = p & 7, k8 = p >> 3;
    int orig = (xcd < r8 ? xcd * (q8 + 1) : r8 * (q8 + 1) + (xcd - r8) * q8) + k8;
    int bx = orig / gridDim.y;       // n-tile  (y-major)
    int by = orig % gridDim.y;       // m-tile
    int bm = by * BM, bn = bx * BN;

    int kLen  = K / SPLITK;
    int kBase = blockIdx.z * kLen;

    auto swz = [](int row) -> int {
        return (KSTEP == 32) ? ((row >> 1) & 3) : (row & 7);
    };

    const ushort* src[RND];
    int dstOff[RND];
#pragma unroll
    for (int r = 0; r < RND; r++) {
        int f = r * THREADS + tid;
        int row = f >> SEGSH, seg = f & (SEGS - 1);
        int lseg = seg ^ swz(row);
        src[r] = (row < BM ? A + (size_t)(bm + row) * K
                           : BT + (size_t)(bn + row - BM) * K) + kBase + lseg * 8;
        dstOff[r] = (r * THREADS + wv * 64) * 8;
    }

    int wm = wv / WN, wn = wv % WN;
    int lr = il & 15;
    int lg = il >> 4;
    int swzR = swz(lr);
    f32x4 acc[MR][NR] = {};

    int nt = kLen / KSTEP;

    // prologue: stage tiles 0..NBUF-2
#pragma unroll
    for (int b = 0; b < NBUF - 1; b++)
#pragma unroll
        for (int r = 0; r < RND; r++)
            gload_lds16(src[r] + b * KSTEP, &S_lds[b * STRIDE + dstOff[r]]);
    waitcnt_vm<RND * (NBUF - 2)>();
    __builtin_amdgcn_s_barrier();

    int cur = 0;
    for (int t = 0; t < nt; ++t) {
        if (t + NBUF - 1 < nt) {
            int sb = cur + NBUF - 1; if (sb >= NBUF) sb -= NBUF;
            int kofs = (t + NBUF - 1) * KSTEP;
            ushort* Bp = &S_lds[sb * STRIDE];
#pragma unroll
            for (int r = 0; r < RND; r++) gload_lds16(src[r] + kofs, &Bp[dstOff[r]]);
        }

        const ushort* base = &S_lds[cur * STRIDE];
        bf16x8 af[KCH][MR], bfr[KCH][NR];
#pragma unroll
        for (int kk = 0; kk < KCH; kk++) {
            int phys = ((kk * 4 + lg) ^ swzR) * 8;
#pragma unroll
            for (int i = 0; i < MR; i++)
                af[kk][i] = *(const bf16x8*)&base[(wm * (BM / WM) + i * 16 + lr) * KSTEP + phys];
#pragma unroll
            for (int i = 0; i < NR; i++)
                bfr[kk][i] = *(const bf16x8*)&base[(BM + wn * (BN / WN) + i * 16 + lr) * KSTEP + phys];
        }
        __builtin_amdgcn_s_setprio(1);
#pragma unroll
        for (int kk = 0; kk < KCH; kk++)
#pragma unroll
            for (int mi = 0; mi < MR; mi++)
#pragma unroll
                for (int ni = 0; ni < NR; ni++)
                    acc[mi][ni] = __builtin_amdgcn_mfma_f32_16x16x32_bf16(
                        af[kk][mi], bfr[kk][ni], acc[mi][ni], 0, 0, 0);
        __builtin_amdgcn_s_setprio(0);

        if (t + 1 < nt) {
            int k = nt - t - 2;
            if (k > NBUF - 2) k = NBUF - 2;
            switch (k) {
                case 0:  waitcnt_vm<0>(); break;
                case 1:  waitcnt_vm<RND>(); break;
                default: waitcnt_vm<2 * RND>(); break;
            }
            __builtin_amdgcn_s_barrier();
        }
        cur = (cur + 1 == NBUF) ? 0 : cur + 1;
    }

    bool addBias = bias && (SPLITK == 1 || blockIdx.z == 0);
    size_t partOfs = PART ? (size_t)blockIdx.z * M * N : 0;
#pragma unroll
    for (int mi = 0; mi < MR; mi++) {
        int row0 = bm + wm * (BM / WM) + mi * 16 + (il >> 4) * 4;
#pragma unroll
        for (int ni = 0; ni < NR; ni++) {
            int col = bn + wn * (BN / WN) + ni * 16 + (il & 15);
            float bv = addBias ? bias[col] : 0.f;
#pragma unroll
            for (int j = 0; j < 4; j++) {
                int r = row0 + j;
                float v = acc[mi][ni][j] + bv;
                if (ACT == 1) v = 0.5f * v * (1.0f + erff(v * 0.70710678118654752f));
                if (RES) v += res[(size_t)r * N + col];
                if (PART) Cf[partOfs + (size_t)r * N + col] = v;
                else if (WF32) Cf[(size_t)r * N + col] = v;
                if (WBF16) {
                    if (VT && bn >= 2 * DM) {
                        int d  = col - 2 * DM;
                        int hh = d >> 6, dd = d & 63;
                        int bb = r >> 9, s = r & (SEQ - 1);
                        Vt[((size_t)(bb * NH + hh) * HD + dd) * SEQ + s] = f2b(v);
                    } else {
                        Cb[(size_t)r * N + col] = f2b(v);
                    }
                }
            }
        }
    }
}

// named wrappers; layer GEMMs: 64x64, KSTEP=64, NBUF=3 (proven R12/R14).
// wo/w2: split-K x4 partial planes (768 blocks = 3.0/CU exact).
// logits: proven 256x256 KSTEP=32 NBUF=4.
__global__ __launch_bounds__(256) void gemm_qkv(
        const ushort* A, const ushort* BT, const float* bias,
        ushort* Cb, ushort* Vt, int M, int N, int K) {
    gemm_body<64, 64, 2, 2, 64, 3, 1, 0, false, false, true, true, false>(
        A, BT, bias, nullptr, nullptr, Cb, Vt, M, N, K);
}
__global__ __launch_bounds__(256) void gemm_wo(
        const ushort* A, const ushort* BT, const float* bias,
        float* Pf, int M, int N, int K) {
    gemm_body<64, 64, 2, 2, 64, 3, SK, 0, false, false, false, false, true>(
        A, BT, bias, nullptr, Pf, nullptr, nullptr, M, N, K);
}
__global__ __launch_bounds__(256) void gemm_w1(
        const ushort* A, const ushort* BT, const float* bias,
        ushort* Cb, int M, int N, int K) {
    gemm_body<64, 64, 2, 2, 64, 3, 1, 1, false, false, true, false, false>(
        A, BT, bias, nullptr, nullptr, Cb, nullptr, M, N, K);
}
__global__ __launch_bounds__(256) void gemm_w2(
        const ushort* A, const ushort* BT, const float* bias,
        float* Pf, int M, int N, int K) {
    gemm_body<64, 64, 2, 2, 64, 3, SK, 0, false, false, false, false, true>(
        A, BT, bias, nullptr, Pf, nullptr, nullptr, M, N, K);
}
__global__ __launch_bounds__(512) void gemm_logits(
        const ushort* A, const ushort* BT, const float* bias,
        float* Cf, int M, int N, int K) {
    gemm_body<256, 256, 2, 4, 32, 4, 1, 0, false, true, false, false, false>(
        A, BT, bias, nullptr, Cf, nullptr, nullptr, M, N, K);
}

// ---------------------------------------------------------------- flash attn
// Proven structure: 32 q-rows, 4 waves, 2-way key-split, staged LDS with
// register prefetch of next tile. Fixed-shift softmax. LDS exactly 40KB
// (was 41KB) -> 4 blocks/CU instead of 3.
__device__ __forceinline__ char* swzp(void* base, int row, int colByte) {
    return (char*)base + ((row * 128 + colByte) ^ ((row & 7) << 4));
}
__device__ __forceinline__ const char* swzpc(const void* base, int row, int colByte) {
    return (const char*)base + ((row * 128 + colByte) ^ ((row & 7) << 4));
}

__global__ __launch_bounds__(256) void fattn_kernel(
        const ushort* __restrict__ qkv, const ushort* __restrict__ vt,
        ushort* __restrict__ ctx) {
    int qt = blockIdx.x;   // 0..15
    int h  = blockIdx.y;
    int b  = blockIdx.z;
    int tid = threadIdx.x;
    int il = tid & 63, wv = tid >> 6;
    int qsub = wv & 1, grp = wv >> 1;

    __shared__ __align__(16) char smem[40 * 1024];
    ushort* Ks = (ushort*)(smem + grp * 8192);
    ushort* Vs = (ushort*)(smem + 16384 + grp * 8192);
    ushort* Ps = (ushort*)(smem + 32768 + wv * 2048);
    float*  Om = (float*)smem;                   // merge alias (8KB)
    float*  Ss = (float*)(smem + 16384);

    int bh = b * NH + h;
    const ushort* kbase = qkv + (size_t)b * SEQ * QKV + DM + h * HD;
    const ushort* vbase = vt + (size_t)bh * HD * SEQ;

    int lr = il & 15, lg = il >> 4;
    int qrow = qt * 32 + qsub * 16 + lr;
    const ushort* qptr = qkv + (size_t)(b * SEQ + qrow) * QKV + h * HD + lg * 8;
    bf16x8 qf0 = *(const bf16x8*)qptr;
    bf16x8 qf1 = *(const bf16x8*)(qptr + 32);

    f32x4 accO[4] = {};
    float sm[4] = {0.f, 0.f, 0.f, 0.f};

    int lig  = qsub * 64 + il;       // 0..127 within key-group
    int srow = lig >> 3;             // 0..15
    int sseg = (lig & 7) * 8;        // 0..56

    // preload tile 0 into registers
    bf16x8 kreg[4], vreg[4];
    {
        int k0 = grp * 256;
#pragma unroll
        for (int r = 0; r < 4; r++) {
            int row = r * 16 + srow;
            kreg[r] = *(const bf16x8*)(kbase + (size_t)(k0 + row) * QKV + sseg);
            vreg[r] = *(const bf16x8*)(vbase + (size_t)row * SEQ + k0 + sseg);
        }
    }

    for (int kt = 0; kt < 4; kt++) {
        __syncthreads();   // prev iter's LDS readers done
#pragma unroll
        for (int r = 0; r < 4; r++) {
            int row = r * 16 + srow;
            *(bf16x8*)swzp(Ks, row, sseg * 2) = kreg[r];
            *(bf16x8*)swzp(Vs, row, sseg * 2) = vreg[r];
        }
        __syncthreads();   // tiles visible

        // prefetch next tile into registers (hides under compute below)
        if (kt < 3) {
            int k0n = grp * 256 + (kt + 1) * 64;
#pragma unroll
            for (int r = 0; r < 4; r++) {
                int row = r * 16 + srow;
                kreg[r] = *(const bf16x8*)(kbase + (size_t)(k0n + row) * QKV + sseg);
                vreg[r] = *(const bf16x8*)(vbase + (size_t)row * SEQ + k0n + sseg);
            }
        }

        // QK^T: S[q 16][key 64]
        f32x4 accS[4] = {};
        __builtin_amdgcn_s_setprio(1);
#pragma unroll
        for (int nf = 0; nf < 4; nf++) {
            bf16x8 b0 = *(const bf16x8*)swzpc(Ks, nf * 16 + lr, lg * 16);
            bf16x8 b1 = *(const bf16x8*)swzpc(Ks, nf * 16 + lr, 64 + lg * 16);
            accS[nf] = __builtin_amdgcn_mfma_f32_16x16x32_bf16(qf0, b0, accS[nf], 0, 0, 0);
            accS[nf] = __builtin_amdgcn_mfma_f32_16x16x32_bf16(qf1, b1, accS[nf], 0, 0, 0);
        }
        __builtin_amdgcn_s_setprio(0);

        // P = exp(s*0.125 - 8); row-sum only (no max tracking)
        float pv[4][4];
#pragma unroll
        for (int nf = 0; nf < 4; nf++)
#pragma unroll
            for (int j = 0; j < 4; j++)
                pv[nf][j] = __expf(fmaf(accS[nf][j], 0.125f, -8.0f));
#pragma unroll
        for (int j = 0; j < 4; j++) {
            float rs = (pv[0][j] + pv[1][j]) + (pv[2][j] + pv[3][j]);
            rs += __shfl_xor(rs, 1, 64);
            rs += __shfl_xor(rs, 2, 64);
            rs += __shfl_xor(rs, 4, 64);
            rs += __shfl_xor(rs, 8, 64);
            sm[j] += rs;
        }

        // P -> LDS (wave-private 16-row tile; re-fragment for PV A-operand)
#pragma unroll
        for (int nf = 0; nf < 4; nf++)
#pragma unroll
            for (int j = 0; j < 4; j++)
                *(ushort*)swzp(Ps, lg * 4 + j, (nf * 16 + lr) * 2) = f2b(pv[nf][j]);

        bf16x8 pa0 = *(const bf16x8*)swzpc(Ps, lr, lg * 16);
        bf16x8 pa1 = *(const bf16x8*)swzpc(Ps, lr, 64 + lg * 16);
        __builtin_amdgcn_s_setprio(1);
#pragma unroll
        for (int nf = 0; nf < 4; nf++) {
            bf16x8 v0 = *(const bf16x8*)swzpc(Vs, nf * 16 + lr, lg * 16);
            bf16x8 v1 = *(const bf16x8*)swzpc(Vs, nf * 16 + lr, 64 + lg * 16);
            accO[nf] = __builtin_amdgcn_mfma_f32_16x16x32_bf16(pa0, v0, accO[nf], 0, 0, 0);
            accO[nf] = __builtin_amdgcn_mfma_f32_16x16x32_bf16(pa1, v1, accO[nf], 0, 0, 0);
        }
        __builtin_amdgcn_s_setprio(0);
    }

    // merge key-halves: plain sums
    __syncthreads();
    if (grp == 1) {
#pragma unroll
        for (int nf = 0; nf < 4; nf++)
#pragma unroll
            for (int j = 0; j < 4; j++)
                Om[(qsub * 16 + lg * 4 + j) * 64 + nf * 16 + lr] = accO[nf][j];
        if (lr == 0) {
#pragma unroll
            for (int j = 0; j < 4; j++)
                Ss[qsub * 16 + lg * 4 + j] = sm[j];
        }
    }
    __syncthreads();
    if (grp == 0) {
        ushort* obase = ctx + (size_t)(b * SEQ + qt * 32 + qsub * 16) * DM + h * HD;
#pragma unroll
        for (int j = 0; j < 4; j++) {
            int q = lg * 4 + j;
            float inv = 1.0f / (sm[j] + Ss[qsub * 16 + q]);
#pragma unroll
            for (int nf = 0; nf < 4; nf++) {
                int d = nf * 16 + lr;
                float o1 = Om[(qsub * 16 + q) * 64 + d];
                obase[(size_t)q * DM + d] = f2b((accO[nf][j] + o1) * inv);
            }
        }
    }
}

// ---------------------------------------------------------------- launch
extern "C" void kernel_launch(void* const* d_in, const int* in_sizes, int n_in,
                              void* d_out, int out_size, void* d_ws, size_t ws_size,
                              hipStream_t stream) {
    const int*   tokens  = (const int*)d_in[0];
    const float* tok_emb = (const float*)d_in[1];
    const float* pos_emb = (const float*)d_in[2];
    const float* ln1_s   = (const float*)d_in[3];
    const float* ln1_b   = (const float*)d_in[4];
    const float* Wq      = (const float*)d_in[5];
    const float* bq      = (const float*)d_in[6];
    const float* Wk      = (const float*)d_in[7];
    const float* bk      = (const float*)d_in[8];
    const float* Wv      = (const float*)d_in[9];
    const float* bv      = (const float*)d_in[10];
    const float* Wo      = (const float*)d_in[11];
    const float* bo      = (const float*)d_in[12];
    const float* ln2_s   = (const float*)d_in[13];
    const float* ln2_b   = (const float*)d_in[14];
    const float* W1      = (const float*)d_in[15];
    const float* b1      = (const float*)d_in[16];
    const float* W2      = (const float*)d_in[17];
    const float* b2      = (const float*)d_in[18];
    const float* W_out   = (const float*)d_in[19];
    const float* b_out   = (const float*)d_in[20];

    char* ws = (char*)d_ws;
    size_t off = 0;
    auto alloc = [&](size_t bytes) { size_t o = off; off = (off + bytes + 255) & ~(size_t)255; return o; };

    float*  x    = (float*)(ws + alloc((size_t)MT * DM * 4));
    float*  pbuf = (float*)(ws + alloc((size_t)SK * MT * DM * 4));  // split-K partials
    ushort* x2b  = (ushort*)(ws + alloc((size_t)MT * DM * 2));
    ushort* qkvb = (ushort*)(ws + alloc((size_t)MT * QKV * 2));
    ushort* cb   = (ushort*)(ws + alloc((size_t)MT * DM * 2));
    ushort* hb   = (ushort*)(ws + alloc((size_t)MT * FF * 2));
    ushort* xb   = (ushort*)(ws + alloc((size_t)MT * DM * 2));
    ushort* vtb  = (ushort*)(ws + alloc((size_t)BATCH * NH * HD * SEQ * 2));
    float*  bqkv = (float*)(ws + alloc((size_t)NL * QKV * 4));

    size_t szQkvT = (size_t)NL * QKV * DM;
    size_t szWoT  = (size_t)NL * DM * DM;
    size_t szW1T  = (size_t)NL * FF * DM;
    size_t szW2T  = (size_t)NL * DM * FF;
    size_t szWoutT= (size_t)NV * DM;

    size_t actEnd = off;
    size_t fullNeed = actEnd + 2 * (szQkvT + szWoT + szW1T + szW2T + szWoutT) + 5 * 256;
    bool full = (fullNeed <= ws_size);

    ushort *WqkvT, *WoT, *W1T, *W2T, *WoutT;
    if (full) {
        WqkvT = (ushort*)(ws + alloc(szQkvT * 2));
        WoT   = (ushort*)(ws + alloc(szWoT * 2));
        W1T   = (ushort*)(ws + alloc(szW1T * 2));
        W2T   = (ushort*)(ws + alloc(szW2T * 2));
        WoutT = (ushort*)(ws + alloc(szWoutT * 2));
    } else {
        size_t layerElems = (size_t)QKV * DM + (size_t)DM * DM + 2 * (size_t)FF * DM;
        size_t regionElems = layerElems > szWoutT ? layerElems : szWoutT;
        ushort* region = (ushort*)(ws + alloc(regionElems * 2));
        WqkvT = region;
        WoT   = WqkvT + (size_t)QKV * DM;
        W1T   = WoT + (size_t)DM * DM;
        W2T   = W1T + (size_t)FF * DM;
        WoutT = region;
    }

    biaspack_kernel<<<(NL * QKV + 255) / 256, 256, 0, stream>>>(bq, bk, bv, bqkv);
    embed_kernel<<<MT, 256, 0, stream>>>(tokens, tok_emb, pos_emb, x);

    if (full) {
        dim3 gD(DM / 64, DM / 128, NL);
        wconv_kernel<<<gD, 256, 0, stream>>>(Wq, WqkvT, DM, DM, (size_t)DM * DM, (size_t)QKV * DM, 0);
        wconv_kernel<<<gD, 256, 0, stream>>>(Wk, WqkvT, DM, DM, (size_t)DM * DM, (size_t)QKV * DM, DM);
        wconv_kernel<<<gD, 256, 0, stream>>>(Wv, WqkvT, DM, DM, (size_t)DM * DM, (size_t)QKV * DM, 2 * DM);
        wconv_kernel<<<gD, 256, 0, stream>>>(Wo, WoT, DM, DM, (size_t)DM * DM, (size_t)DM * DM, 0);
        dim3 g1(FF / 64, DM / 128, NL);
        wconv_kernel<<<g1, 256, 0, stream>>>(W1, W1T, DM, FF, (size_t)DM * FF, (size_t)FF * DM, 0);
        dim3 g2(DM / 64, FF / 128, NL);
        wconv_kernel<<<g2, 256, 0, stream>>>(W2, W2T, FF, DM, (size_t)FF * DM, (size_t)DM * FF, 0);
        dim3 go(NV / 64, DM / 128, 1);
        wconv_kernel<<<go, 256, 0, stream>>>(W_out, WoutT, DM, NV, 0, 0, 0);
    }

    for (int l = 0; l < NL; l++) {
        ushort* wqkv = WqkvT + (full ? (size_t)l * QKV * DM : 0);
        ushort* wo   = WoT   + (full ? (size_t)l * DM * DM  : 0);
        ushort* w1   = W1T   + (full ? (size_t)l * FF * DM  : 0);
        ushort* w2   = W2T   + (full ? (size_t)l * DM * FF  : 0);
        if (!full) {
            dim3 gD(DM / 64, DM / 128, 1);
            wconv_kernel<<<gD, 256, 0, stream>>>(Wq + (size_t)l * DM * DM, wqkv, DM, DM, 0, 0, 0);
            wconv_kernel<<<gD, 256, 0, stream>>>(Wk + (size_t)l * DM * DM, wqkv, DM, DM, 0, 0, DM);
            wconv_kernel<<<gD, 256, 0, stream>>>(Wv + (size_t)l * DM * DM, wqkv, DM, DM, 0, 0, 2 * DM);
            wconv_kernel<<<gD, 256, 0, stream>>>(Wo + (size_t)l * DM * DM, wo, DM, DM, 0, 0, 0);
            dim3 g1(FF / 64, DM / 128, 1);
            wconv_kernel<<<g1, 256, 0, stream>>>(W1 + (size_t)l * DM * FF, w1, DM, FF, 0, 0, 0);
            dim3 g2(DM / 64, FF / 128, 1);
            wconv_kernel<<<g2, 256, 0, stream>>>(W2 + (size_t)l * FF * DM, w2, FF, DM, 0, 0, 0);
        }

        // ln1: l==0 plain; l>0 folds previous layer's w2 partials into x
        ln_kernel<<<MT, 256, 0, stream>>>(x, l == 0 ? nullptr : pbuf,
                                          ln1_s + l * DM, ln1_b + l * DM, x2b, x);

        // QKV GEMM (64x64, KSTEP=64); V n-tiles written transposed to vtb
        gemm_qkv<<<dim3(QKV / 64, MT / 64), 256, 0, stream>>>(
            x2b, wqkv, bqkv + (size_t)l * QKV, qkvb, vtb, MT, QKV, DM);

        fattn_kernel<<<dim3(SEQ / 32, NH, BATCH), 256, 0, stream>>>(qkvb, vtb, cb);

        // ctx @ Wo + bo -> SK partial planes (plain stores, no atomics)
        gemm_wo<<<dim3(DM / 64, MT / 64, SK), 256, 0, stream>>>(
            cb, wo, bo + (size_t)l * DM, pbuf, MT, DM, DM);

        // ln2 folds wo partials: x += sum(P), then LN
        ln_kernel<<<MT, 256, 0, stream>>>(x, pbuf,
                                          ln2_s + l * DM, ln2_b + l * DM, x2b, x);

        // W1 GEMM (64x64, KSTEP=64)
        gemm_w1<<<dim3(FF / 64, MT / 64), 256, 0, stream>>>(
            x2b, w1, b1 + (size_t)l * FF, hb, MT, FF, DM);

        // h @ W2 + b2 -> SK partial planes (folded by next ln1 / final fold)
        gemm_w2<<<dim3(DM / 64, MT / 64, SK), 256, 0, stream>>>(
            hb, w2, b2 + (size_t)l * DM, pbuf, MT, DM, FF);
    }

    if (!full) {
        dim3 go(NV / 64, DM / 128, 1);
        wconv_kernel<<<go, 256, 0, stream>>>(W_out, WoutT, DM, NV, 0, 0, 0);
    }
    // fold last w2 partials + convert to bf16
    fold_kernel<<<(MT * DM + 255) / 256, 256, 0, stream>>>(x, pbuf, xb, MT * DM);

    // logits: 256x256 tile, 8 waves (2x4), KSTEP=32 NBUF=4 (proven path)
    gemm_logits<<<dim3(NV / 256, MT / 256), 512, 0, stream>>>(
        xb, WoutT, b_out, (float*)d_out, MT, NV, DM);
}

// Round 16
// 1108.165 us; speedup vs baseline: 1.0662x; 1.0024x over previous
//
#include <hip/hip_runtime.h>
#include <hip/hip_bf16.h>
#include <math.h>

// GPT-1 forward: B=2 S=512 D=768 H=12 DFF=3072 L=12 V=32000
constexpr int BATCH = 2;
constexpr int SEQ   = 512;
constexpr int DM    = 768;
constexpr int NH    = 12;
constexpr int FF    = 3072;
constexpr int NL    = 12;
constexpr int NV    = 32000;
constexpr int HD    = 64;
constexpr int MT    = BATCH * SEQ; // 1024 token rows
constexpr int QKV   = 3 * DM;      // 2304
constexpr int SK    = 4;           // split-K planes for wo/w2

typedef __attribute__((ext_vector_type(8))) short bf16x8;
typedef __attribute__((ext_vector_type(4))) float f32x4;

__device__ __forceinline__ float b2f(ushort u) {
    return __uint_as_float(((unsigned)u) << 16);
}
__device__ __forceinline__ ushort f2b(float f) {
    __hip_bfloat16 h = __float2bfloat16(f);
    return *reinterpret_cast<ushort*>(&h);
}

template<int N>
__device__ __forceinline__ void waitcnt_vm() {
    if constexpr (N == 0) asm volatile("s_waitcnt vmcnt(0)" ::: "memory");
    else if constexpr (N == 2) asm volatile("s_waitcnt vmcnt(2)" ::: "memory");
    else if constexpr (N == 3) asm volatile("s_waitcnt vmcnt(3)" ::: "memory");
    else if constexpr (N == 4) asm volatile("s_waitcnt vmcnt(4)" ::: "memory");
    else if constexpr (N == 6) asm volatile("s_waitcnt vmcnt(6)" ::: "memory");
    else if constexpr (N == 8) asm volatile("s_waitcnt vmcnt(8)" ::: "memory");
    else if constexpr (N == 12) asm volatile("s_waitcnt vmcnt(12)" ::: "memory");
}

// ---------------------------------------------------------------- embedding
__global__ void embed_kernel(const int* __restrict__ tokens,
                             const float* __restrict__ tok_emb,
                             const float* __restrict__ pos_emb,
                             float* __restrict__ x) {
    int m = blockIdx.x;
    int s = m % SEQ;
    int t = tokens[m];
    const float* te = tok_emb + (size_t)t * DM;
    const float* pe = pos_emb + (size_t)s * DM;
    float* row = x + (size_t)m * DM;
    for (int d = threadIdx.x; d < DM; d += blockDim.x)
        row[d] = te[d] + pe[d];
}

// ------------------------------------------------- weight convert+transpose
// in: f32 [l][K][N]; out: bf16 [l][N][K]. Tile 64 n x 128 k.
__global__ __launch_bounds__(256) void wconv_kernel(
        const float* __restrict__ W, ushort* __restrict__ out,
        int K, int N, size_t inLS, size_t outLS, int nOff) {
    int l  = blockIdx.z;
    int n0 = blockIdx.x * 64;
    int k0 = blockIdx.y * 128;
    int tid = threadIdx.x;
    __shared__ float t[2][64][65];   // [k-half][k%64][n]
    const float* src = W + (size_t)l * inLS + (size_t)k0 * N + n0;
    int r  = tid >> 4;           // 0..15
    int c4 = (tid & 15) * 4;     // 0..60
#pragma unroll
    for (int i = 0; i < 8; i++) {
        int krow = i * 16 + r;           // 0..127
        float4 v = *(const float4*)(src + (size_t)krow * N + c4);
        float* dstl = &t[krow >> 6][krow & 63][c4];
        dstl[0] = v.x; dstl[1] = v.y; dstl[2] = v.z; dstl[3] = v.w;
    }
    __syncthreads();
    ushort* dst = out + (size_t)l * outLS;
    int kk = (tid & 15) * 8;     // 0..120 (lane's 8-elem k chunk)
    int h  = kk >> 6;            // half
    int kb = kk & 63;
#pragma unroll
    for (int j = 0; j < 4; j++) {
        int n = j * 16 + (tid >> 4);     // 0..63
        ushort o[8];
#pragma unroll
        for (int m = 0; m < 8; m++) o[m] = f2b(t[h][kb + m][n]);
        *(ushort4*)(dst + (size_t)(nOff + n0 + n) * K + k0 + kk)     = *(ushort4*)&o[0];
        *(ushort4*)(dst + (size_t)(nOff + n0 + n) * K + k0 + kk + 4) = *(ushort4*)&o[4];
    }
}

// ---------------------------------------------------------------- bias pack
__global__ void biaspack_kernel(const float* __restrict__ bq,
                                const float* __restrict__ bk,
                                const float* __restrict__ bv,
                                float* __restrict__ bqkv) {
    int idx = blockIdx.x * 256 + threadIdx.x;
    if (idx >= NL * QKV) return;
    int l = idx / QKV, c = idx % QKV;
    float v;
    if (c < DM)            v = bq[l * DM + c];
    else if (c < 2 * DM)   v = bk[l * DM + c - DM];
    else                   v = bv[l * DM + c - 2 * DM];
    bqkv[idx] = v;
}

// --------------------------------------------------------- fold + f32->bf16
// xb = bf16(x + P0..P3)   (final-layer w2 partial fold)
__global__ void fold_kernel(const float* __restrict__ x, const float* __restrict__ pb,
                            ushort* __restrict__ out, int n) {
    int i = blockIdx.x * 256 + threadIdx.x;
    if (i < n) out[i] = f2b(x[i] + (pb[i] + pb[n + i]) + (pb[2 * n + i] + pb[3 * n + i]));
}

// ---------------------------------------------------------------- layernorm
// If pb != null: xs = x + sum of SK partial planes, write xs back to xw,
// then y = LN(xs)*sc + bi. Else plain LN(x).
__global__ __launch_bounds__(256) void ln_kernel(const float* __restrict__ x,
                                                 const float* __restrict__ pb,
                                                 const float* __restrict__ sc,
                                                 const float* __restrict__ bi,
                                                 ushort* __restrict__ y,
                                                 float* __restrict__ xw) {
    int m = blockIdx.x;
    int t = threadIdx.x;
    const float* row = x + (size_t)m * DM;
    float vals[3];
    float s0 = 0.f, s1 = 0.f;
#pragma unroll
    for (int i = 0; i < 3; i++) {
        int d = t + 256 * i;
        float v = row[d];
        if (pb) {
            size_t idx = (size_t)m * DM + d;
            v += (pb[idx] + pb[(size_t)MT * DM + idx])
               + (pb[2 * (size_t)MT * DM + idx] + pb[3 * (size_t)MT * DM + idx]);
        }
        vals[i] = v;
        s0 += v;
        s1 += v * v;
    }
    if (pb) {
        float* wrow = xw + (size_t)m * DM;
#pragma unroll
        for (int i = 0; i < 3; i++) wrow[t + 256 * i] = vals[i];
    }
#pragma unroll
    for (int off = 32; off >= 1; off >>= 1) {
        s0 += __shfl_down(s0, off, 64);
        s1 += __shfl_down(s1, off, 64);
    }
    __shared__ float r0[4], r1[4];
    __shared__ float mu_s, rs_s;
    int wid = t >> 6, lane = t & 63;
    if (lane == 0) { r0[wid] = s0; r1[wid] = s1; }
    __syncthreads();
    if (t == 0) {
        float a = r0[0] + r0[1] + r0[2] + r0[3];
        float q = r1[0] + r1[1] + r1[2] + r1[3];
        float mu  = a / DM;
        float var = q / DM - mu * mu;
        mu_s = mu;
        rs_s = rsqrtf(var + 1e-5f);
    }
    __syncthreads();
    float mu = mu_s, rs = rs_s;
    ushort* orow = y + (size_t)m * DM;
#pragma unroll
    for (int i = 0; i < 3; i++) {
        int d = t + 256 * i;
        orow[d] = f2b((vals[i] - mu) * rs * sc[d] + bi[d]);
    }
}

// ---------------------------------------------------------------- MFMA GEMM
__device__ __forceinline__ void gload_lds16(const void* g, void* l) {
    __builtin_amdgcn_global_load_lds(
        (const __attribute__((address_space(1))) void*)g,
        (__attribute__((address_space(3))) void*)l, 16, 0, 0);
}

template<int BM, int BN, int WM, int WN, int KSTEP, int NBUF, int SPLITK, int ACT,
         bool RES, bool WF32, bool WBF16, bool VT, bool PART>
__device__ __forceinline__ void gemm_body(
        const ushort* __restrict__ A, const ushort* __restrict__ BT,
        const float* __restrict__ bias, const float* __restrict__ res,
        float* __restrict__ Cf, ushort* __restrict__ Cb, ushort* __restrict__ Vt,
        int M, int N, int K) {
    constexpr int THREADS = WM * WN * 64;
    constexpr int ROWS    = BM + BN;
    constexpr int SEGS    = KSTEP / 8;           // 16B segments per row
    constexpr int SEGSH   = (KSTEP == 32) ? 2 : 3;
    constexpr int RND     = ROWS * KSTEP / (THREADS * 8);
    constexpr int MR      = BM / WM / 16;
    constexpr int NR      = BN / WN / 16;
    constexpr int KCH     = KSTEP / 32;          // mfma k-subtiles per step
    constexpr int STRIDE  = ROWS * KSTEP;        // ushorts per buffer
    __shared__ ushort S_lds[NBUF * STRIDE];
    int tid = threadIdx.x;
    int il = tid & 63, wv = tid >> 6;

    // bijective XCD-chunked swizzle
    int p   = blockIdx.x + gridDim.x * blockIdx.y;
    int nwg = gridDim.x * gridDim.y;
    int q8  = nwg >> 3, r8 = nwg & 7;
    int xcd = p & 7, k8 = p >> 3;
    int orig = (xcd < r8 ? xcd * (q8 + 1) : r8 * (q8 + 1) + (xcd - r8) * q8) + k8;
    int bx = orig / gridDim.y;       // n-tile  (y-major)
    int by = orig % gridDim.y;       // m-tile
    int bm = by * BM, bn = bx * BN;

    int kLen  = K / SPLITK;
    int kBase = blockIdx.z * kLen;

    auto swz = [](int row) -> int {
        return (KSTEP == 32) ? ((row >> 1) & 3) : (row & 7);
    };

    const ushort* src[RND];
    int dstOff[RND];
#pragma unroll
    for (int r = 0; r < RND; r++) {
        int f = r * THREADS + tid;
        int row = f >> SEGSH, seg = f & (SEGS - 1);
        int lseg = seg ^ swz(row);
        src[r] = (row < BM ? A + (size_t)(bm + row) * K
                           : BT + (size_t)(bn + row - BM) * K) + kBase + lseg * 8;
        dstOff[r] = (r * THREADS + wv * 64) * 8;
    }

    int wm = wv / WN, wn = wv % WN;
    int lr = il & 15;
    int lg = il >> 4;
    int swzR = swz(lr);
    f32x4 acc[MR][NR] = {};

    int nt = kLen / KSTEP;

    // prologue: stage tiles 0..NBUF-2
#pragma unroll
    for (int b = 0; b < NBUF - 1; b++)
#pragma unroll
        for (int r = 0; r < RND; r++)
            gload_lds16(src[r] + b * KSTEP, &S_lds[b * STRIDE + dstOff[r]]);
    waitcnt_vm<RND * (NBUF - 2)>();
    __builtin_amdgcn_s_barrier();

    int cur = 0;
    for (int t = 0; t < nt; ++t) {
        if (t + NBUF - 1 < nt) {
            int sb = cur + NBUF - 1; if (sb >= NBUF) sb -= NBUF;
            int kofs = (t + NBUF - 1) * KSTEP;
            ushort* Bp = &S_lds[sb * STRIDE];
#pragma unroll
            for (int r = 0; r < RND; r++) gload_lds16(src[r] + kofs, &Bp[dstOff[r]]);
        }

        const ushort* base = &S_lds[cur * STRIDE];
        bf16x8 af[KCH][MR], bfr[KCH][NR];
#pragma unroll
        for (int kk = 0; kk < KCH; kk++) {
            int phys = ((kk * 4 + lg) ^ swzR) * 8;
#pragma unroll
            for (int i = 0; i < MR; i++)
                af[kk][i] = *(const bf16x8*)&base[(wm * (BM / WM) + i * 16 + lr) * KSTEP + phys];
#pragma unroll
            for (int i = 0; i < NR; i++)
                bfr[kk][i] = *(const bf16x8*)&base[(BM + wn * (BN / WN) + i * 16 + lr) * KSTEP + phys];
        }
        __builtin_amdgcn_s_setprio(1);
#pragma unroll
        for (int kk = 0; kk < KCH; kk++)
#pragma unroll
            for (int mi = 0; mi < MR; mi++)
#pragma unroll
                for (int ni = 0; ni < NR; ni++)
                    acc[mi][ni] = __builtin_amdgcn_mfma_f32_16x16x32_bf16(
                        af[kk][mi], bfr[kk][ni], acc[mi][ni], 0, 0, 0);
        __builtin_amdgcn_s_setprio(0);

        if (t + 1 < nt) {
            int k = nt - t - 2;
            if (k > NBUF - 2) k = NBUF - 2;
            switch (k) {
                case 0:  waitcnt_vm<0>(); break;
                case 1:  waitcnt_vm<RND>(); break;
                default: waitcnt_vm<2 * RND>(); break;
            }
            __builtin_amdgcn_s_barrier();
        }
        cur = (cur + 1 == NBUF) ? 0 : cur + 1;
    }

    bool addBias = bias && (SPLITK == 1 || blockIdx.z == 0);
    size_t partOfs = PART ? (size_t)blockIdx.z * M * N : 0;
#pragma unroll
    for (int mi = 0; mi < MR; mi++) {
        int row0 = bm + wm * (BM / WM) + mi * 16 + (il >> 4) * 4;
#pragma unroll
        for (int ni = 0; ni < NR; ni++) {
            int col = bn + wn * (BN / WN) + ni * 16 + (il & 15);
            float bv = addBias ? bias[col] : 0.f;
#pragma unroll
            for (int j = 0; j < 4; j++) {
                int r = row0 + j;
                float v = acc[mi][ni][j] + bv;
                if (ACT == 1) v = 0.5f * v * (1.0f + erff(v * 0.70710678118654752f));
                if (RES) v += res[(size_t)r * N + col];
                if (PART) Cf[partOfs + (size_t)r * N + col] = v;
                else if (WF32) Cf[(size_t)r * N + col] = v;
                if (WBF16) {
                    if (VT && bn >= 2 * DM) {
                        int d  = col - 2 * DM;
                        int hh = d >> 6, dd = d & 63;
                        int bb = r >> 9, s = r & (SEQ - 1);
                        Vt[((size_t)(bb * NH + hh) * HD + dd) * SEQ + s] = f2b(v);
                    } else {
                        Cb[(size_t)r * N + col] = f2b(v);
                    }
                }
            }
        }
    }
}

// named wrappers; layer GEMMs: 64x64, KSTEP=64, NBUF=3 (proven R12/R14).
__global__ __launch_bounds__(256) void gemm_qkv(
        const ushort* A, const ushort* BT, const float* bias,
        ushort* Cb, ushort* Vt, int M, int N, int K) {
    gemm_body<64, 64, 2, 2, 64, 3, 1, 0, false, false, true, true, false>(
        A, BT, bias, nullptr, nullptr, Cb, Vt, M, N, K);
}
__global__ __launch_bounds__(256) void gemm_wo(
        const ushort* A, const ushort* BT, const float* bias,
        float* Pf, int M, int N, int K) {
    gemm_body<64, 64, 2, 2, 64, 3, SK, 0, false, false, false, false, true>(
        A, BT, bias, nullptr, Pf, nullptr, nullptr, M, N, K);
}
__global__ __launch_bounds__(256) void gemm_w1(
        const ushort* A, const ushort* BT, const float* bias,
        ushort* Cb, int M, int N, int K) {
    gemm_body<64, 64, 2, 2, 64, 3, 1, 1, false, false, true, false, false>(
        A, BT, bias, nullptr, nullptr, Cb, nullptr, M, N, K);
}
__global__ __launch_bounds__(256) void gemm_w2(
        const ushort* A, const ushort* BT, const float* bias,
        float* Pf, int M, int N, int K) {
    gemm_body<64, 64, 2, 2, 64, 3, SK, 0, false, false, false, false, true>(
        A, BT, bias, nullptr, Pf, nullptr, nullptr, M, N, K);
}

// ------------------------------------------------- logits: phase-scheduled
// 256x256 tile, 8 waves (2m x 4n), K=768 as 12 tiles of 64, each tile in two
// 32-k halves. LDS = 2 slots x 2 halves x (A[256][32]+B[256][32]) = 128KB.
// Per phase: stage ONE unit (A+B half of a future tile, 4 gload_lds/thread),
// counted vmcnt(12) (3 units stay in flight; tail 8/4/0), barrier,
// 12 ds_read_b128, 32 MFMA/wave, barrier. Stage targets exactly the half
// freed by the preceding phase's end barrier:
//   phase0 of tile t stages U(t+1,h1)  [region freed at (t-1,p1) end]
//   phase1 of tile t stages U(t+2,h0)  [region freed at (t,p0) end]
// Prologue stages U(0,0),U(0,1),U(1,0). Seg-XOR swizzle (row>>1)&3 both on
// staged global src and frag reads (2 lanes/bank).
__global__ __launch_bounds__(512) void gemm_logits(
        const ushort* __restrict__ A, const ushort* __restrict__ BT,
        const float* __restrict__ bias, float* __restrict__ Cf,
        int M, int N, int K) {
    constexpr int NT = 12;             // 768 / 64
    __shared__ ushort S[4][16384];     // [slot*2+half][A 256x32 | B 256x32]
    int tid = threadIdx.x;
    int il = tid & 63, wv = tid >> 6;
    int wm = wv >> 2, wn = wv & 3;

    int p   = blockIdx.x + gridDim.x * blockIdx.y;
    int nwg = gridDim.x * gridDim.y;
    int q8  = nwg >> 3, r8 = nwg & 7;
    int xcd = p & 7, k8 = p >> 3;
    int orig = (xcd < r8 ? xcd * (q8 + 1) : r8 * (q8 + 1) + (xcd - r8) * q8) + k8;
    int bx = orig / gridDim.y;
    int by = orig % gridDim.y;
    int bm = by * 256, bn = bx * 256;

    const ushort* srcb[4];
    int dsto[4];
#pragma unroll
    for (int ldi = 0; ldi < 4; ldi++) {
        int f = ldi * 512 + tid;
        int row = f >> 2, seg = f & 3;
        int lseg = seg ^ ((row >> 1) & 3);
        srcb[ldi] = (row < 256 ? A + (size_t)(bm + row) * K
                               : BT + (size_t)(bn + row - 256) * K) + lseg * 8;
        dsto[ldi] = f * 8;
    }

    int lr = il & 15, lg = il >> 4;
    int xseg = (lg ^ ((lr >> 1) & 3)) * 8;
    f32x4 acc[8][4] = {};

    auto STAGE = [&](int T, int h) {
        ushort* reg = S[(T & 1) * 2 + h];
        int kb = T * 64 + h * 32;
#pragma unroll
        for (int ldi = 0; ldi < 4; ldi++)
            gload_lds16(srcb[ldi] + kb, &reg[dsto[ldi]]);
    };
    auto PHASE = [&](int T, int h) {
        __builtin_amdgcn_s_barrier();
        const ushort* reg = S[(T & 1) * 2 + h];
        bf16x8 af[8], bf[4];
#pragma unroll
        for (int i = 0; i < 8; i++)
            af[i] = *(const bf16x8*)&reg[(wm * 128 + i * 16 + lr) * 32 + xseg];
#pragma unroll
        for (int j = 0; j < 4; j++)
            bf[j] = *(const bf16x8*)&reg[8192 + (wn * 64 + j * 16 + lr) * 32 + xseg];
        __builtin_amdgcn_s_setprio(1);
#pragma unroll
        for (int i = 0; i < 8; i++)
#pragma unroll
            for (int j = 0; j < 4; j++)
                acc[i][j] = __builtin_amdgcn_mfma_f32_16x16x32_bf16(
                    af[i], bf[j], acc[i][j], 0, 0, 0);
        __builtin_amdgcn_s_setprio(0);
        __builtin_amdgcn_s_barrier();
    };

    // prologue
    STAGE(0, 0); STAGE(0, 1); STAGE(1, 0);

    for (int t = 0; t < NT; ++t) {
        // phase 0: consume (t, h0)
        if (t + 1 < NT) { STAGE(t + 1, 1); waitcnt_vm<12>(); }
        else            { waitcnt_vm<4>(); }
        PHASE(t, 0);
        // phase 1: consume (t, h1)
        if (t + 2 < NT)      { STAGE(t + 2, 0); waitcnt_vm<12>(); }
        else if (t + 1 < NT) { waitcnt_vm<8>(); }
        else                 { waitcnt_vm<0>(); }
        PHASE(t, 1);
    }

    // epilogue: C/D layout col=il&15, row=(il>>4)*4+j
#pragma unroll
    for (int mi = 0; mi < 8; mi++) {
        int row0 = bm + wm * 128 + mi * 16 + (il >> 4) * 4;
#pragma unroll
        for (int ni = 0; ni < 4; ni++) {
            int col = bn + wn * 64 + ni * 16 + (il & 15);
            float bv = bias[col];
#pragma unroll
            for (int j = 0; j < 4; j++) {
                int r = row0 + j;
                Cf[(size_t)r * N + col] = acc[mi][ni][j] + bv;
            }
        }
    }
}

// ---------------------------------------------------------------- flash attn
// Proven structure: 32 q-rows, 4 waves, 2-way key-split, staged LDS with
// register prefetch of next tile. Fixed-shift softmax. LDS 40KB.
__device__ __forceinline__ char* swzp(void* base, int row, int colByte) {
    return (char*)base + ((row * 128 + colByte) ^ ((row & 7) << 4));
}
__device__ __forceinline__ const char* swzpc(const void* base, int row, int colByte) {
    return (const char*)base + ((row * 128 + colByte) ^ ((row & 7) << 4));
}

__global__ __launch_bounds__(256) void fattn_kernel(
        const ushort* __restrict__ qkv, const ushort* __restrict__ vt,
        ushort* __restrict__ ctx) {
    int qt = blockIdx.x;   // 0..15
    int h  = blockIdx.y;
    int b  = blockIdx.z;
    int tid = threadIdx.x;
    int il = tid & 63, wv = tid >> 6;
    int qsub = wv & 1, grp = wv >> 1;

    __shared__ __align__(16) char smem[40 * 1024];
    ushort* Ks = (ushort*)(smem + grp * 8192);
    ushort* Vs = (ushort*)(smem + 16384 + grp * 8192);
    ushort* Ps = (ushort*)(smem + 32768 + wv * 2048);
    float*  Om = (float*)smem;                   // merge alias (8KB)
    float*  Ss = (float*)(smem + 16384);

    int bh = b * NH + h;
    const ushort* kbase = qkv + (size_t)b * SEQ * QKV + DM + h * HD;
    const ushort* vbase = vt + (size_t)bh * HD * SEQ;

    int lr = il & 15, lg = il >> 4;
    int qrow = qt * 32 + qsub * 16 + lr;
    const ushort* qptr = qkv + (size_t)(b * SEQ + qrow) * QKV + h * HD + lg * 8;
    bf16x8 qf0 = *(const bf16x8*)qptr;
    bf16x8 qf1 = *(const bf16x8*)(qptr + 32);

    f32x4 accO[4] = {};
    float sm[4] = {0.f, 0.f, 0.f, 0.f};

    int lig  = qsub * 64 + il;       // 0..127 within key-group
    int srow = lig >> 3;             // 0..15
    int sseg = (lig & 7) * 8;        // 0..56

    // preload tile 0 into registers
    bf16x8 kreg[4], vreg[4];
    {
        int k0 = grp * 256;
#pragma unroll
        for (int r = 0; r < 4; r++) {
            int row = r * 16 + srow;
            kreg[r] = *(const bf16x8*)(kbase + (size_t)(k0 + row) * QKV + sseg);
            vreg[r] = *(const bf16x8*)(vbase + (size_t)row * SEQ + k0 + sseg);
        }
    }

    for (int kt = 0; kt < 4; kt++) {
        __syncthreads();   // prev iter's LDS readers done
#pragma unroll
        for (int r = 0; r < 4; r++) {
            int row = r * 16 + srow;
            *(bf16x8*)swzp(Ks, row, sseg * 2) = kreg[r];
            *(bf16x8*)swzp(Vs, row, sseg * 2) = vreg[r];
        }
        __syncthreads();   // tiles visible

        // prefetch next tile into registers (hides under compute below)
        if (kt < 3) {
            int k0n = grp * 256 + (kt + 1) * 64;
#pragma unroll
            for (int r = 0; r < 4; r++) {
                int row = r * 16 + srow;
                kreg[r] = *(const bf16x8*)(kbase + (size_t)(k0n + row) * QKV + sseg);
                vreg[r] = *(const bf16x8*)(vbase + (size_t)row * SEQ + k0n + sseg);
            }
        }

        // QK^T: S[q 16][key 64]
        f32x4 accS[4] = {};
        __builtin_amdgcn_s_setprio(1);
#pragma unroll
        for (int nf = 0; nf < 4; nf++) {
            bf16x8 b0 = *(const bf16x8*)swzpc(Ks, nf * 16 + lr, lg * 16);
            bf16x8 b1 = *(const bf16x8*)swzpc(Ks, nf * 16 + lr, 64 + lg * 16);
            accS[nf] = __builtin_amdgcn_mfma_f32_16x16x32_bf16(qf0, b0, accS[nf], 0, 0, 0);
            accS[nf] = __builtin_amdgcn_mfma_f32_16x16x32_bf16(qf1, b1, accS[nf], 0, 0, 0);
        }
        __builtin_amdgcn_s_setprio(0);

        // P = exp(s*0.125 - 8); row-sum only (no max tracking)
        float pv[4][4];
#pragma unroll
        for (int nf = 0; nf < 4; nf++)
#pragma unroll
            for (int j = 0; j < 4; j++)
                pv[nf][j] = __expf(fmaf(accS[nf][j], 0.125f, -8.0f));
#pragma unroll
        for (int j = 0; j < 4; j++) {
            float rs = (pv[0][j] + pv[1][j]) + (pv[2][j] + pv[3][j]);
            rs += __shfl_xor(rs, 1, 64);
            rs += __shfl_xor(rs, 2, 64);
            rs += __shfl_xor(rs, 4, 64);
            rs += __shfl_xor(rs, 8, 64);
            sm[j] += rs;
        }

        // P -> LDS (wave-private 16-row tile; re-fragment for PV A-operand)
#pragma unroll
        for (int nf = 0; nf < 4; nf++)
#pragma unroll
            for (int j = 0; j < 4; j++)
                *(ushort*)swzp(Ps, lg * 4 + j, (nf * 16 + lr) * 2) = f2b(pv[nf][j]);

        bf16x8 pa0 = *(const bf16x8*)swzpc(Ps, lr, lg * 16);
        bf16x8 pa1 = *(const bf16x8*)swzpc(Ps, lr, 64 + lg * 16);
        __builtin_amdgcn_s_setprio(1);
#pragma unroll
        for (int nf = 0; nf < 4; nf++) {
            bf16x8 v0 = *(const bf16x8*)swzpc(Vs, nf * 16 + lr, lg * 16);
            bf16x8 v1 = *(const bf16x8*)swzpc(Vs, nf * 16 + lr, 64 + lg * 16);
            accO[nf] = __builtin_amdgcn_mfma_f32_16x16x32_bf16(pa0, v0, accO[nf], 0, 0, 0);
            accO[nf] = __builtin_amdgcn_mfma_f32_16x16x32_bf16(pa1, v1, accO[nf], 0, 0, 0);
        }
        __builtin_amdgcn_s_setprio(0);
    }

    // merge key-halves: plain sums
    __syncthreads();
    if (grp == 1) {
#pragma unroll
        for (int nf = 0; nf < 4; nf++)
#pragma unroll
            for (int j = 0; j < 4; j++)
                Om[(qsub * 16 + lg * 4 + j) * 64 + nf * 16 + lr] = accO[nf][j];
        if (lr == 0) {
#pragma unroll
            for (int j = 0; j < 4; j++)
                Ss[qsub * 16 + lg * 4 + j] = sm[j];
        }
    }
    __syncthreads();
    if (grp == 0) {
        ushort* obase = ctx + (size_t)(b * SEQ + qt * 32 + qsub * 16) * DM + h * HD;
#pragma unroll
        for (int j = 0; j < 4; j++) {
            int q = lg * 4 + j;
            float inv = 1.0f / (sm[j] + Ss[qsub * 16 + q]);
#pragma unroll
            for (int nf = 0; nf < 4; nf++) {
                int d = nf * 16 + lr;
                float o1 = Om[(qsub * 16 + q) * 64 + d];
                obase[(size_t)q * DM + d] = f2b((accO[nf][j] + o1) * inv);
            }
        }
    }
}

// ---------------------------------------------------------------- launch
extern "C" void kernel_launch(void* const* d_in, const int* in_sizes, int n_in,
                              void* d_out, int out_size, void* d_ws, size_t ws_size,
                              hipStream_t stream) {
    const int*   tokens  = (const int*)d_in[0];
    const float* tok_emb = (const float*)d_in[1];
    const float* pos_emb = (const float*)d_in[2];
    const float* ln1_s   = (const float*)d_in[3];
    const float* ln1_b   = (const float*)d_in[4];
    const float* Wq      = (const float*)d_in[5];
    const float* bq      = (const float*)d_in[6];
    const float* Wk      = (const float*)d_in[7];
    const float* bk      = (const float*)d_in[8];
    const float* Wv      = (const float*)d_in[9];
    const float* bv      = (const float*)d_in[10];
    const float* Wo      = (const float*)d_in[11];
    const float* bo      = (const float*)d_in[12];
    const float* ln2_s   = (const float*)d_in[13];
    const float* ln2_b   = (const float*)d_in[14];
    const float* W1      = (const float*)d_in[15];
    const float* b1      = (const float*)d_in[16];
    const float* W2      = (const float*)d_in[17];
    const float* b2      = (const float*)d_in[18];
    const float* W_out   = (const float*)d_in[19];
    const float* b_out   = (const float*)d_in[20];

    char* ws = (char*)d_ws;
    size_t off = 0;
    auto alloc = [&](size_t bytes) { size_t o = off; off = (off + bytes + 255) & ~(size_t)255; return o; };

    float*  x    = (float*)(ws + alloc((size_t)MT * DM * 4));
    float*  pbuf = (float*)(ws + alloc((size_t)SK * MT * DM * 4));  // split-K partials
    ushort* x2b  = (ushort*)(ws + alloc((size_t)MT * DM * 2));
    ushort* qkvb = (ushort*)(ws + alloc((size_t)MT * QKV * 2));
    ushort* cb   = (ushort*)(ws + alloc((size_t)MT * DM * 2));
    ushort* hb   = (ushort*)(ws + alloc((size_t)MT * FF * 2));
    ushort* xb   = (ushort*)(ws + alloc((size_t)MT * DM * 2));
    ushort* vtb  = (ushort*)(ws + alloc((size_t)BATCH * NH * HD * SEQ * 2));
    float*  bqkv = (float*)(ws + alloc((size_t)NL * QKV * 4));

    size_t szQkvT = (size_t)NL * QKV * DM;
    size_t szWoT  = (size_t)NL * DM * DM;
    size_t szW1T  = (size_t)NL * FF * DM;
    size_t szW2T  = (size_t)NL * DM * FF;
    size_t szWoutT= (size_t)NV * DM;

    size_t actEnd = off;
    size_t fullNeed = actEnd + 2 * (szQkvT + szWoT + szW1T + szW2T + szWoutT) + 5 * 256;
    bool full = (fullNeed <= ws_size);

    ushort *WqkvT, *WoT, *W1T, *W2T, *WoutT;
    if (full) {
        WqkvT = (ushort*)(ws + alloc(szQkvT * 2));
        WoT   = (ushort*)(ws + alloc(szWoT * 2));
        W1T   = (ushort*)(ws + alloc(szW1T * 2));
        W2T   = (ushort*)(ws + alloc(szW2T * 2));
        WoutT = (ushort*)(ws + alloc(szWoutT * 2));
    } else {
        size_t layerElems = (size_t)QKV * DM + (size_t)DM * DM + 2 * (size_t)FF * DM;
        size_t regionElems = layerElems > szWoutT ? layerElems : szWoutT;
        ushort* region = (ushort*)(ws + alloc(regionElems * 2));
        WqkvT = region;
        WoT   = WqkvT + (size_t)QKV * DM;
        W1T   = WoT + (size_t)DM * DM;
        W2T   = W1T + (size_t)FF * DM;
        WoutT = region;
    }

    biaspack_kernel<<<(NL * QKV + 255) / 256, 256, 0, stream>>>(bq, bk, bv, bqkv);
    embed_kernel<<<MT, 256, 0, stream>>>(tokens, tok_emb, pos_emb, x);

    if (full) {
        dim3 gD(DM / 64, DM / 128, NL);
        wconv_kernel<<<gD, 256, 0, stream>>>(Wq, WqkvT, DM, DM, (size_t)DM * DM, (size_t)QKV * DM, 0);
        wconv_kernel<<<gD, 256, 0, stream>>>(Wk, WqkvT, DM, DM, (size_t)DM * DM, (size_t)QKV * DM, DM);
        wconv_kernel<<<gD, 256, 0, stream>>>(Wv, WqkvT, DM, DM, (size_t)DM * DM, (size_t)QKV * DM, 2 * DM);
        wconv_kernel<<<gD, 256, 0, stream>>>(Wo, WoT, DM, DM, (size_t)DM * DM, (size_t)DM * DM, 0);
        dim3 g1(FF / 64, DM / 128, NL);
        wconv_kernel<<<g1, 256, 0, stream>>>(W1, W1T, DM, FF, (size_t)DM * FF, (size_t)FF * DM, 0);
        dim3 g2(DM / 64, FF / 128, NL);
        wconv_kernel<<<g2, 256, 0, stream>>>(W2, W2T, FF, DM, (size_t)FF * DM, (size_t)DM * FF, 0);
        dim3 go(NV / 64, DM / 128, 1);
        wconv_kernel<<<go, 256, 0, stream>>>(W_out, WoutT, DM, NV, 0, 0, 0);
    }

    for (int l = 0; l < NL; l++) {
        ushort* wqkv = WqkvT + (full ? (size_t)l * QKV * DM : 0);
        ushort* wo   = WoT   + (full ? (size_t)l * DM * DM  : 0);
        ushort* w1   = W1T   + (full ? (size_t)l * FF * DM  : 0);
        ushort* w2   = W2T   + (full ? (size_t)l * DM * FF  : 0);
        if (!full) {
            dim3 gD(DM / 64, DM / 128, 1);
            wconv_kernel<<<gD, 256, 0, stream>>>(Wq + (size_t)l * DM * DM, wqkv, DM, DM, 0, 0, 0);
            wconv_kernel<<<gD, 256, 0, stream>>>(Wk + (size_t)l * DM * DM, wqkv, DM, DM, 0, 0, DM);
            wconv_kernel<<<gD, 256, 0, stream>>>(Wv + (size_t)l * DM * DM, wqkv, DM, DM, 0, 0, 2 * DM);
            wconv_kernel<<<gD, 256, 0, stream>>>(Wo + (size_t)l * DM * DM, wo, DM, DM, 0, 0, 0);
            dim3 g1(FF / 64, DM / 128, 1);
            wconv_kernel<<<g1, 256, 0, stream>>>(W1 + (size_t)l * DM * FF, w1, DM, FF, 0, 0, 0);
            dim3 g2(DM / 64, FF / 128, 1);
            wconv_kernel<<<g2, 256, 0, stream>>>(W2 + (size_t)l * FF * DM, w2, FF, DM, 0, 0, 0);
        }

        // ln1: l==0 plain; l>0 folds previous layer's w2 partials into x
        ln_kernel<<<MT, 256, 0, stream>>>(x, l == 0 ? nullptr : pbuf,
                                          ln1_s + l * DM, ln1_b + l * DM, x2b, x);

        // QKV GEMM (64x64, KSTEP=64); V n-tiles written transposed to vtb
        gemm_qkv<<<dim3(QKV / 64, MT / 64), 256, 0, stream>>>(
            x2b, wqkv, bqkv + (size_t)l * QKV, qkvb, vtb, MT, QKV, DM);

        fattn_kernel<<<dim3(SEQ / 32, NH, BATCH), 256, 0, stream>>>(qkvb, vtb, cb);

        // ctx @ Wo + bo -> SK partial planes (plain stores, no atomics)
        gemm_wo<<<dim3(DM / 64, MT / 64, SK), 256, 0, stream>>>(
            cb, wo, bo + (size_t)l * DM, pbuf, MT, DM, DM);

        // ln2 folds wo partials: x += sum(P), then LN
        ln_kernel<<<MT, 256, 0, stream>>>(x, pbuf,
                                          ln2_s + l * DM, ln2_b + l * DM, x2b, x);

        // W1 GEMM (64x64, KSTEP=64)
        gemm_w1<<<dim3(FF / 64, MT / 64), 256, 0, stream>>>(
            x2b, w1, b1 + (size_t)l * FF, hb, MT, FF, DM);

        // h @ W2 + b2 -> SK partial planes (folded by next ln1 / final fold)
        gemm_w2<<<dim3(DM / 64, MT / 64, SK), 256, 0, stream>>>(
            hb, w2, b2 + (size_t)l * DM, pbuf, MT, DM, FF);
    }

    if (!full) {
        dim3 go(NV / 64, DM / 128, 1);
        wconv_kernel<<<go, 256, 0, stream>>>(W_out, WoutT, DM, NV, 0, 0, 0);
    }
    // fold last w2 partials + convert to bf16
    fold_kernel<<<(MT * DM + 255) / 256, 256, 0, stream>>>(x, pbuf, xb, MT * DM);

    // logits: phase-scheduled 256x256, 128KB LDS, counted vmcnt(12)
    gemm_logits<<<dim3(NV / 256, MT / 256), 512, 0, stream>>>(
        xb, WoutT, b_out, (float*)d_out, MT, NV, DM);
}